// Round 1
// baseline (573.691 us; speedup 1.0000x reference)
//
#include <hip/hip_runtime.h>
#include <hip/hip_bf16.h>

// ---------- types / helpers ----------
typedef short short8 __attribute__((ext_vector_type(8)));
typedef float floatx4 __attribute__((ext_vector_type(4)));

typedef __attribute__((address_space(1))) unsigned int as1_u32;
typedef __attribute__((address_space(3))) unsigned int as3_u32;

__device__ __forceinline__ void load_lds16(const void* g, void* l) {
  // async 16B/lane global->LDS; HW dest = wave-uniform base + lane*16
  __builtin_amdgcn_global_load_lds((const as1_u32*)g, (as3_u32*)l, 16, 0, 0);
}

__device__ __forceinline__ unsigned short f2bf(float f) {
  __bf16 h = (__bf16)f;
  return __builtin_bit_cast(unsigned short, h);
}
__device__ __forceinline__ float bf2f(unsigned short u) {
  unsigned int x = ((unsigned int)u) << 16;
  return __builtin_bit_cast(float, x);
}

// ---------- constants ----------
#define TB 2
#define TT 2048
#define TC 2048
#define TH 32
#define THKV 8
#define TD 64
#define QKVN 3072   // 2048 Q + 512 K + 512 V
#define KOFF 2048
#define VOFF 2560

// ---------- 0: cast fp32 -> bf16 (x, packed Wqkv, Wo) ----------
__global__ __launch_bounds__(256) void cast_all(
    const float* __restrict__ x, const float* __restrict__ wq,
    const float* __restrict__ wk, const float* __restrict__ wv,
    const float* __restrict__ wo,
    unsigned short* __restrict__ xb, unsigned short* __restrict__ wqkv,
    unsigned short* __restrict__ wob) {
  long i4 = (long)blockIdx.x * 256 + threadIdx.x;  // float4 index
  const float* src;
  unsigned short* dst;
  if (i4 < 2097152)      { src = x;  dst = xb; }
  else if (i4 < 3145728) { src = wq; dst = wqkv;           i4 -= 2097152; }
  else if (i4 < 3407872) { src = wk; dst = wqkv + 4194304; i4 -= 3145728; }
  else if (i4 < 3670016) { src = wv; dst = wqkv + 5242880; i4 -= 3407872; }
  else                   { src = wo; dst = wob;            i4 -= 3670016; }
  float4 v = ((const float4*)src)[i4];
  ushort4 o;
  o.x = f2bf(v.x); o.y = f2bf(v.y); o.z = f2bf(v.z); o.w = f2bf(v.w);
  ((ushort4*)dst)[i4] = o;
}

// ---------- 1: NT GEMM  C[M,N] = A[M,K] * B[N,K]^T  (bf16 in, fp32 acc) ----------
__device__ __forceinline__ void store_val(float* p, float v) { *p = v; }
__device__ __forceinline__ void store_val(unsigned short* p, float v) { *p = f2bf(v); }

template <typename OutT>
__global__ __launch_bounds__(256) void gemm_nt(const unsigned short* __restrict__ A,
                                               const unsigned short* __restrict__ Bw,
                                               OutT* __restrict__ C,
                                               int M, int N, int K) {
  __shared__ unsigned short As[128 * 64];
  __shared__ unsigned short Bs[128 * 64];
  const int tid = threadIdx.x;
  const int lane = tid & 63, w = tid >> 6;
  const int quad = lane >> 4, l15 = lane & 15;
  const int wm = w >> 1, wn = w & 1;
  const int m0 = blockIdx.y * 128, n0 = blockIdx.x * 128;

  floatx4 acc[4][4];
#pragma unroll
  for (int i = 0; i < 4; ++i)
#pragma unroll
    for (int j = 0; j < 4; ++j) acc[i][j] = (floatx4){0.f, 0.f, 0.f, 0.f};

  const int ar = tid >> 3;         // 0..31 (row within 32-row pass)
  const int ac = (tid & 7) * 8;    // k-offset within 64 k-tile
  const unsigned short* Abase = A + (size_t)(m0 + ar) * K + ac;
  const unsigned short* Bbase = Bw + (size_t)(n0 + ar) * K + ac;

  for (int k0 = 0; k0 < K; k0 += 64) {
    __syncthreads();
#pragma unroll
    for (int p = 0; p < 4; ++p) {
      load_lds16(Abase + (size_t)(p * 32) * K + k0, (char*)As + p * 4096 + tid * 16);
      load_lds16(Bbase + (size_t)(p * 32) * K + k0, (char*)Bs + p * 4096 + tid * 16);
    }
    __syncthreads();
#pragma unroll
    for (int ks = 0; ks < 2; ++ks) {
      short8 af[4], bfr[4];
#pragma unroll
      for (int i = 0; i < 4; ++i)
        af[i] = *(const short8*)(As + (wm * 64 + i * 16 + l15) * 64 + ks * 32 + quad * 8);
#pragma unroll
      for (int j = 0; j < 4; ++j)
        bfr[j] = *(const short8*)(Bs + (wn * 64 + j * 16 + l15) * 64 + ks * 32 + quad * 8);
#pragma unroll
      for (int i = 0; i < 4; ++i)
#pragma unroll
        for (int j = 0; j < 4; ++j)
          acc[i][j] = __builtin_amdgcn_mfma_f32_16x16x32_bf16(af[i], bfr[j], acc[i][j], 0, 0, 0);
    }
  }
  // epilogue: C/D layout col=lane&15, row=quad*4+reg (m89-verified)
#pragma unroll
  for (int i = 0; i < 4; ++i) {
    const int row = m0 + wm * 64 + i * 16 + quad * 4;
#pragma unroll
    for (int j = 0; j < 4; ++j) {
      const int col = n0 + wn * 64 + j * 16 + l15;
#pragma unroll
      for (int r = 0; r < 4; ++r)
        store_val(C + (size_t)(row + r) * N + col, acc[i][j][r]);
    }
  }
}

// ---------- 2: RoPE in-place on Q and K halves of qkv [4096, 3072] bf16 ----------
__global__ __launch_bounds__(256) void rope_kernel(unsigned short* __restrict__ qkv) {
  const int idx = blockIdx.x * 256 + threadIdx.x;  // < 4096*1280
  const int row = idx / 1280;
  const int p = idx - row * 1280;
  const int t = row & (TT - 1);
  int col, d;
  if (p < 1024) { d = p & 31; col = (p >> 5) * 64 + d; }
  else { const int p2 = p - 1024; d = p2 & 31; col = KOFF + (p2 >> 5) * 64 + d; }
  const size_t base = (size_t)row * QKVN + col;
  const float a = bf2f(qkv[base]);
  const float b = bf2f(qkv[base + 32]);
  const float inv = powf(10000.f, -(float)d * (1.f / 32.f));
  float sn, cs;
  sincosf((float)t * inv, &sn, &cs);
  qkv[base]      = f2bf(a * cs - b * sn);
  qkv[base + 32] = f2bf(b * cs + a * sn);
}

// ---------- 3: causal flash attention ----------
// grid (16, 32, 2) = (qtile, head, batch); 256 threads; 128 q-rows/block, 64-kv tiles
__global__ __launch_bounds__(256) void attn_kernel(const unsigned short* __restrict__ qkv,
                                                   unsigned short* __restrict__ attn) {
  const int qt = blockIdx.x, h = blockIdx.y, b = blockIdx.z;
  const int hk = h >> 2;
  const int tid = threadIdx.x;
  const int w = tid >> 6, lane = tid & 63, quad = lane >> 4, l15 = lane & 15;

  __shared__ char lds[35840];
  unsigned short* Qs = (unsigned short*)lds;             // [128][64] (overlay, init only)
  unsigned short* Ks = (unsigned short*)lds;             // [64][64]
  unsigned short* Vt = (unsigned short*)(lds + 8192);    // [64][72] (transposed V, padded)
  unsigned short* Ps = (unsigned short*)(lds + 17408);   // 4 x [32][72]
  unsigned short* Psw = Ps + w * (32 * 72);

  const size_t rowQ = (size_t)(b * TT + qt * 128);

  // stage Q tile (128x64) via async 16B loads
  {
    const unsigned short* qb = qkv + (rowQ + (tid >> 3)) * QKVN + h * 64 + (tid & 7) * 8;
#pragma unroll
    for (int p = 0; p < 4; ++p)
      load_lds16(qb + (size_t)p * 32 * QKVN, lds + p * 4096 + tid * 16);
  }
  __syncthreads();
  short8 qf[2][2];  // per-wave 32 q-rows, A-operand frags (kept in regs for whole kernel)
#pragma unroll
  for (int i = 0; i < 2; ++i)
#pragma unroll
    for (int ks = 0; ks < 2; ++ks)
      qf[i][ks] = *(const short8*)(Qs + (w * 32 + i * 16 + l15) * 64 + ks * 32 + quad * 8);

  floatx4 accO[2][4];
  float m_run[2][4], l_run[2][4];
#pragma unroll
  for (int i = 0; i < 2; ++i)
#pragma unroll
    for (int r = 0; r < 4; ++r) { m_run[i][r] = -1e30f; l_run[i][r] = 0.f; }
#pragma unroll
  for (int i = 0; i < 2; ++i)
#pragma unroll
    for (int j = 0; j < 4; ++j) accO[i][j] = (floatx4){0.f, 0.f, 0.f, 0.f};

  const int ktmax = 2 * qt + 1;
  for (int kt = 0; kt <= ktmax; ++kt) {
    __syncthreads();  // prev iter's LDS reads done (also covers Q-frag extraction on kt=0)
    // stage K tile (64x64) async
    const unsigned short* kb =
        qkv + (size_t)(b * TT + kt * 64 + (tid >> 3)) * QKVN + KOFF + hk * 64 + (tid & 7) * 8;
    load_lds16(kb, lds + tid * 16);
    load_lds16(kb + (size_t)32 * QKVN, lds + 4096 + tid * 16);
    // stage V tile transposed: Vt[d][kk]
    const unsigned short* vb =
        qkv + (size_t)(b * TT + kt * 64 + (tid >> 3)) * QKVN + VOFF + hk * 64 + (tid & 7) * 8;
#pragma unroll
    for (int p = 0; p < 2; ++p) {
      uint4 vv = *(const uint4*)(vb + (size_t)p * 32 * QKVN);
      const unsigned short* vs = (const unsigned short*)&vv;
      const int r = p * 32 + (tid >> 3);
      const int dbase = (tid & 7) * 8;
#pragma unroll
      for (int e = 0; e < 8; ++e) Vt[(dbase + e) * 72 + r] = vs[e];
    }
    __syncthreads();

    // S = Q K^T  (per wave: 32 q-rows x 64 kk)
    floatx4 s[2][4];
#pragma unroll
    for (int j = 0; j < 4; ++j) {
      const short8 kf0 = *(const short8*)(Ks + (j * 16 + l15) * 64 + quad * 8);
      const short8 kf1 = *(const short8*)(Ks + (j * 16 + l15) * 64 + 32 + quad * 8);
#pragma unroll
      for (int i = 0; i < 2; ++i) {
        floatx4 z = (floatx4){0.f, 0.f, 0.f, 0.f};
        z = __builtin_amdgcn_mfma_f32_16x16x32_bf16(qf[i][0], kf0, z, 0, 0, 0);
        s[i][j] = __builtin_amdgcn_mfma_f32_16x16x32_bf16(qf[i][1], kf1, z, 0, 0, 0);
      }
    }

    const bool domask = (kt >= 2 * qt);
#pragma unroll
    for (int i = 0; i < 2; ++i) {
      float mx[4], rs[4], al[4];
#pragma unroll
      for (int r = 0; r < 4; ++r) mx[r] = -1e30f;
#pragma unroll
      for (int j = 0; j < 4; ++j) {
        const int kg = kt * 64 + j * 16 + l15;
#pragma unroll
        for (int r = 0; r < 4; ++r) {
          float sv = s[i][j][r] * 0.125f;  // 1/sqrt(64)
          if (domask) {
            const int qg = qt * 128 + w * 32 + i * 16 + quad * 4 + r;
            if (kg > qg) sv = -1e30f;
          }
          s[i][j][r] = sv;
          mx[r] = fmaxf(mx[r], sv);
        }
      }
#pragma unroll
      for (int r = 0; r < 4; ++r) {
        mx[r] = fmaxf(mx[r], __shfl_xor(mx[r], 1));
        mx[r] = fmaxf(mx[r], __shfl_xor(mx[r], 2));
        mx[r] = fmaxf(mx[r], __shfl_xor(mx[r], 4));
        mx[r] = fmaxf(mx[r], __shfl_xor(mx[r], 8));
        const float mnew = fmaxf(m_run[i][r], mx[r]);
        al[r] = __expf(m_run[i][r] - mnew);
        m_run[i][r] = mnew;
        rs[r] = 0.f;
      }
#pragma unroll
      for (int j = 0; j < 4; ++j) {
#pragma unroll
        for (int r = 0; r < 4; ++r) {
          const float pv = __expf(s[i][j][r] - m_run[i][r]);
          rs[r] += pv;
          Psw[(i * 16 + quad * 4 + r) * 72 + j * 16 + l15] = f2bf(pv);
        }
      }
#pragma unroll
      for (int r = 0; r < 4; ++r) {
        rs[r] += __shfl_xor(rs[r], 1);
        rs[r] += __shfl_xor(rs[r], 2);
        rs[r] += __shfl_xor(rs[r], 4);
        rs[r] += __shfl_xor(rs[r], 8);
        l_run[i][r] = l_run[i][r] * al[r] + rs[r];
#pragma unroll
        for (int jd = 0; jd < 4; ++jd) accO[i][jd][r] *= al[r];
      }
    }
    asm volatile("s_waitcnt lgkmcnt(0)" ::: "memory");  // wave-local P writes -> reads

    // O += P V   (P: A-operand from LDS round-trip; V: B-operand from transposed tile)
#pragma unroll
    for (int ks = 0; ks < 2; ++ks) {
      short8 pf[2];
#pragma unroll
      for (int i = 0; i < 2; ++i)
        pf[i] = *(const short8*)(Psw + (i * 16 + l15) * 72 + ks * 32 + quad * 8);
#pragma unroll
      for (int jd = 0; jd < 4; ++jd) {
        const short8 vf = *(const short8*)(Vt + (jd * 16 + l15) * 72 + ks * 32 + quad * 8);
#pragma unroll
        for (int i = 0; i < 2; ++i)
          accO[i][jd] = __builtin_amdgcn_mfma_f32_16x16x32_bf16(pf[i], vf, accO[i][jd], 0, 0, 0);
      }
    }
  }

  // epilogue: O / l -> attn [4096, 2048] bf16
#pragma unroll
  for (int i = 0; i < 2; ++i) {
#pragma unroll
    for (int jd = 0; jd < 4; ++jd) {
      const int col = h * 64 + jd * 16 + l15;
#pragma unroll
      for (int r = 0; r < 4; ++r) {
        const size_t row = rowQ + w * 32 + i * 16 + quad * 4 + r;
        attn[row * TC + col] = f2bf(accO[i][jd][r] / l_run[i][r]);
      }
    }
  }
}

// ---------- launch ----------
extern "C" void kernel_launch(void* const* d_in, const int* in_sizes, int n_in,
                              void* d_out, int out_size, void* d_ws, size_t ws_size,
                              hipStream_t stream) {
  const float* x = (const float*)d_in[0];
  const float* Wq = (const float*)d_in[1];
  const float* Wk = (const float*)d_in[2];
  const float* Wv = (const float*)d_in[3];
  const float* Wo = (const float*)d_in[4];
  float* out = (float*)d_out;

  char* ws = (char*)d_ws;
  unsigned short* xb   = (unsigned short*)(ws);                       // 4096x2048 bf16
  unsigned short* wqkv = (unsigned short*)(ws + 16777216);            // 3072x2048 bf16
  unsigned short* wob  = (unsigned short*)(ws + 16777216 + 12582912); // 2048x2048 bf16
  unsigned short* qkv  = (unsigned short*)(ws + 37748736);            // 4096x3072 bf16
  unsigned short* attn = (unsigned short*)(ws + 62914560);            // 4096x2048 bf16
  // total ws use: 79,691,776 bytes

  cast_all<<<18432, 256, 0, stream>>>(x, Wq, Wk, Wv, Wo, xb, wqkv, wob);
  gemm_nt<unsigned short><<<dim3(QKVN / 128, 4096 / 128), 256, 0, stream>>>(
      xb, wqkv, qkv, 4096, QKVN, 2048);
  rope_kernel<<<20480, 256, 0, stream>>>(qkv);
  attn_kernel<<<dim3(16, 32, 2), 256, 0, stream>>>(qkv, attn);
  gemm_nt<float><<<dim3(TC / 128, 4096 / 128), 256, 0, stream>>>(
      attn, wob, out, 4096, TC, 2048);
}

// Round 2
// 523.362 us; speedup vs baseline: 1.0962x; 1.0962x over previous
//
#include <hip/hip_runtime.h>
#include <hip/hip_bf16.h>
#include <math.h>

// ---------- types / helpers ----------
typedef short short8 __attribute__((ext_vector_type(8)));
typedef float floatx4 __attribute__((ext_vector_type(4)));

typedef __attribute__((address_space(1))) unsigned int as1_u32;
typedef __attribute__((address_space(3))) unsigned int as3_u32;

__device__ __forceinline__ void load_lds16(const void* g, void* l) {
  // async 16B/lane global->LDS; HW dest = wave-uniform base + lane*16
  __builtin_amdgcn_global_load_lds((const as1_u32*)g, (as3_u32*)l, 16, 0, 0);
}

__device__ __forceinline__ unsigned short f2bf(float f) {
  __bf16 h = (__bf16)f;
  return __builtin_bit_cast(unsigned short, h);
}
__device__ __forceinline__ float bf2f(unsigned short u) {
  unsigned int x = ((unsigned int)u) << 16;
  return __builtin_bit_cast(float, x);
}

// ---------- constants ----------
#define TB 2
#define TT 2048
#define TC 2048
#define TH 32
#define THKV 8
#define TD 64
#define QKVN 3072   // 2048 Q + 512 K + 512 V
#define KOFF 2048
#define VOFF 2560

// ---------- 0: cast fp32 -> bf16 (x, packed Wqkv, Wo) ----------
__global__ __launch_bounds__(256) void cast_all(
    const float* __restrict__ x, const float* __restrict__ wq,
    const float* __restrict__ wk, const float* __restrict__ wv,
    const float* __restrict__ wo,
    unsigned short* __restrict__ xb, unsigned short* __restrict__ wqkv,
    unsigned short* __restrict__ wob) {
  long i4 = (long)blockIdx.x * 256 + threadIdx.x;  // float4 index
  const float* src;
  unsigned short* dst;
  if (i4 < 2097152)      { src = x;  dst = xb; }
  else if (i4 < 3145728) { src = wq; dst = wqkv;           i4 -= 2097152; }
  else if (i4 < 3407872) { src = wk; dst = wqkv + 4194304; i4 -= 3145728; }
  else if (i4 < 3670016) { src = wv; dst = wqkv + 5242880; i4 -= 3407872; }
  else                   { src = wo; dst = wob;            i4 -= 3670016; }
  float4 v = ((const float4*)src)[i4];
  ushort4 o;
  o.x = f2bf(v.x); o.y = f2bf(v.y); o.z = f2bf(v.z); o.w = f2bf(v.w);
  ((ushort4*)dst)[i4] = o;
}

// ---------- 1: NT GEMM  C[M,N] = A[M,K] * B[N,K]^T  (bf16 in, fp32 acc) ----------
__device__ __forceinline__ void store_val(float* p, float v) { *p = v; }
__device__ __forceinline__ void store_val(unsigned short* p, float v) { *p = f2bf(v); }

template <typename OutT>
__global__ __launch_bounds__(256) void gemm_nt(const unsigned short* __restrict__ A,
                                               const unsigned short* __restrict__ Bw,
                                               OutT* __restrict__ C,
                                               int M, int N, int K) {
  __shared__ unsigned short As[128 * 64];
  __shared__ unsigned short Bs[128 * 64];
  const int tid = threadIdx.x;
  const int lane = tid & 63, w = tid >> 6;
  const int quad = lane >> 4, l15 = lane & 15;
  const int wm = w >> 1, wn = w & 1;
  const int m0 = blockIdx.y * 128, n0 = blockIdx.x * 128;

  floatx4 acc[4][4];
#pragma unroll
  for (int i = 0; i < 4; ++i)
#pragma unroll
    for (int j = 0; j < 4; ++j) acc[i][j] = (floatx4){0.f, 0.f, 0.f, 0.f};

  const int ar = tid >> 3;         // 0..31 (row within 32-row pass)
  const int ac = (tid & 7) * 8;    // k-offset within 64 k-tile
  const unsigned short* Abase = A + (size_t)(m0 + ar) * K + ac;
  const unsigned short* Bbase = Bw + (size_t)(n0 + ar) * K + ac;

  for (int k0 = 0; k0 < K; k0 += 64) {
    __syncthreads();
#pragma unroll
    for (int p = 0; p < 4; ++p) {
      load_lds16(Abase + (size_t)(p * 32) * K + k0, (char*)As + p * 4096 + tid * 16);
      load_lds16(Bbase + (size_t)(p * 32) * K + k0, (char*)Bs + p * 4096 + tid * 16);
    }
    __syncthreads();
#pragma unroll
    for (int ks = 0; ks < 2; ++ks) {
      short8 af[4], bfr[4];
#pragma unroll
      for (int i = 0; i < 4; ++i)
        af[i] = *(const short8*)(As + (wm * 64 + i * 16 + l15) * 64 + ks * 32 + quad * 8);
#pragma unroll
      for (int j = 0; j < 4; ++j)
        bfr[j] = *(const short8*)(Bs + (wn * 64 + j * 16 + l15) * 64 + ks * 32 + quad * 8);
#pragma unroll
      for (int i = 0; i < 4; ++i)
#pragma unroll
        for (int j = 0; j < 4; ++j)
          acc[i][j] = __builtin_amdgcn_mfma_f32_16x16x32_bf16(af[i], bfr[j], acc[i][j], 0, 0, 0);
    }
  }
  // epilogue: C/D layout col=lane&15, row=quad*4+reg (m89-verified)
#pragma unroll
  for (int i = 0; i < 4; ++i) {
    const int row = m0 + wm * 64 + i * 16 + quad * 4;
#pragma unroll
    for (int j = 0; j < 4; ++j) {
      const int col = n0 + wn * 64 + j * 16 + l15;
#pragma unroll
      for (int r = 0; r < 4; ++r)
        store_val(C + (size_t)(row + r) * N + col, acc[i][j][r]);
    }
  }
}

// ---------- 2: RoPE in-place on Q and K halves of qkv [4096, 3072] bf16 ----------
__global__ __launch_bounds__(256) void rope_kernel(unsigned short* __restrict__ qkv) {
  const int idx = blockIdx.x * 256 + threadIdx.x;  // < 4096*1280
  const int row = idx / 1280;
  const int p = idx - row * 1280;
  const int t = row & (TT - 1);
  int col, d;
  if (p < 1024) { d = p & 31; col = (p >> 5) * 64 + d; }
  else { const int p2 = p - 1024; d = p2 & 31; col = KOFF + (p2 >> 5) * 64 + d; }
  const size_t base = (size_t)row * QKVN + col;
  const float a = bf2f(qkv[base]);
  const float b = bf2f(qkv[base + 32]);
  const float inv = powf(10000.f, -(float)d * (1.f / 32.f));
  float sn, cs;
  sincosf((float)t * inv, &sn, &cs);
  qkv[base]      = f2bf(a * cs - b * sn);
  qkv[base + 32] = f2bf(b * cs + a * sn);
}

// ---------- 3: causal flash attention (double-buffered, swizzled LDS) ----------
// grid (16, 32, 2) = (qtile, head, batch); 256 threads; 128 q-rows/block, 64-kv tiles
// LDS: Ks[2] 2x8192B | Vt[2] 2x9216B (stride 72, XOR-swizzled cols) | Ps 4x4608B
#define LDS_K(buf) ((unsigned short*)(lds + (buf) * 8192))
#define LDS_V(buf) ((unsigned short*)(lds + 16384 + (buf) * 9216))
#define LDS_P      ((unsigned short*)(lds + 34816))

__global__ __launch_bounds__(256) void attn_kernel(const unsigned short* __restrict__ qkv,
                                                   unsigned short* __restrict__ attn) {
  const int qt = 15 - blockIdx.x;  // long blocks dispatch first
  const int h = blockIdx.y, b = blockIdx.z;
  const int hk = h >> 2;
  const int tid = threadIdx.x;
  const int w = tid >> 6, lane = tid & 63, quad = lane >> 4, l15 = lane & 15;

  __shared__ char lds[53248];
  unsigned short* Psw = LDS_P + w * 2304;   // [32][72] per wave, quad-swizzled cols

  const size_t rowQ = (size_t)(b * TT + qt * 128);

  // ---- stage Q tile (128x64) into Ks region, extract A-frags to regs ----
  {
    const unsigned short* qb = qkv + (rowQ + (tid >> 3)) * QKVN + h * 64 + (tid & 7) * 8;
#pragma unroll
    for (int p = 0; p < 4; ++p)
      load_lds16(qb + (size_t)p * 32 * QKVN, lds + p * 4096 + tid * 16);
  }
  __syncthreads();
  short8 qf[2][2];
#pragma unroll
  for (int i = 0; i < 2; ++i)
#pragma unroll
    for (int ks = 0; ks < 2; ++ks)
      qf[i][ks] = *(const short8*)((unsigned short*)lds +
                                   (w * 32 + i * 16 + l15) * 64 + ks * 32 + quad * 8);
  __syncthreads();  // all waves done reading Q region before K(0) overwrites it

  floatx4 accO[2][4], accL[2];
  float m_run[2][4];
#pragma unroll
  for (int i = 0; i < 2; ++i) {
    accL[i] = (floatx4){0.f, 0.f, 0.f, 0.f};
#pragma unroll
    for (int r = 0; r < 4; ++r) m_run[i][r] = -1e30f;
#pragma unroll
    for (int j = 0; j < 4; ++j) accO[i][j] = (floatx4){0.f, 0.f, 0.f, 0.f};
  }

  const unsigned short* kbase = qkv + KOFF + (size_t)hk * 64;
  const unsigned short* vbase = qkv + VOFF + (size_t)hk * 64;
  const int vr = tid >> 3;           // kv row this thread transposes (plus +32)
  const int vd = (tid & 7) * 8;      // d base (8 elements)
  const int vkey = 8 * (tid & 7);    // XOR swizzle key = 8*(d>>3)

  const short8 ones = {16256, 16256, 16256, 16256, 16256, 16256, 16256, 16256};  // bf16 1.0

  // ---- prologue: tile 0 ----
  {
    const unsigned short* kb =
        kbase + (size_t)(b * TT + (tid >> 3)) * QKVN + (tid & 7) * 8;
    load_lds16(kb, (char*)LDS_K(0) + tid * 16);
    load_lds16(kb + (size_t)32 * QKVN, (char*)LDS_K(0) + 4096 + tid * 16);
    const unsigned short* vb = vbase + (size_t)(b * TT + vr) * QKVN + vd;
    uint4 v0 = *(const uint4*)(vb);
    uint4 v1 = *(const uint4*)(vb + (size_t)32 * QKVN);
    unsigned short* Vt = LDS_V(0);
    const unsigned short* s0 = (const unsigned short*)&v0;
    const unsigned short* s1 = (const unsigned short*)&v1;
#pragma unroll
    for (int e = 0; e < 8; ++e) {
      Vt[(vd + e) * 72 + (vr ^ vkey)] = s0[e];
      Vt[(vd + e) * 72 + ((vr + 32) ^ vkey)] = s1[e];
    }
  }
  __syncthreads();

  const int ktmax = 2 * qt + 1;
  for (int kt = 0; kt <= ktmax; ++kt) {
    const int cur = kt & 1, nxt = cur ^ 1;
    // ---- issue next tile's loads BEFORE compute (latency hidden by compute) ----
    uint4 v0, v1;
    if (kt < ktmax) {
      const unsigned short* kb =
          kbase + (size_t)(b * TT + (kt + 1) * 64 + (tid >> 3)) * QKVN + (tid & 7) * 8;
      load_lds16(kb, (char*)LDS_K(nxt) + tid * 16);
      load_lds16(kb + (size_t)32 * QKVN, (char*)LDS_K(nxt) + 4096 + tid * 16);
      const unsigned short* vb = vbase + (size_t)(b * TT + (kt + 1) * 64 + vr) * QKVN + vd;
      v0 = *(const uint4*)(vb);
      v1 = *(const uint4*)(vb + (size_t)32 * QKVN);
    }

    // ---- S = Q K^T ----
    const unsigned short* Ks = LDS_K(cur);
    floatx4 s[2][4];
#pragma unroll
    for (int j = 0; j < 4; ++j) {
      const short8 kf0 = *(const short8*)(Ks + (j * 16 + l15) * 64 + quad * 8);
      const short8 kf1 = *(const short8*)(Ks + (j * 16 + l15) * 64 + 32 + quad * 8);
#pragma unroll
      for (int i = 0; i < 2; ++i) {
        floatx4 z = (floatx4){0.f, 0.f, 0.f, 0.f};
        z = __builtin_amdgcn_mfma_f32_16x16x32_bf16(qf[i][0], kf0, z, 0, 0, 0);
        s[i][j] = __builtin_amdgcn_mfma_f32_16x16x32_bf16(qf[i][1], kf1, z, 0, 0, 0);
      }
    }

    // ---- online softmax (exp2 domain); P -> LDS (quad-swizzled) ----
    const bool domask = (kt >= 2 * qt);
    const float SC = 0.18033688f;  // (1/8) * log2(e)
#pragma unroll
    for (int i = 0; i < 2; ++i) {
      float mx[4], al[4];
#pragma unroll
      for (int r = 0; r < 4; ++r) mx[r] = -1e30f;
#pragma unroll
      for (int j = 0; j < 4; ++j) {
        const int kg = kt * 64 + j * 16 + l15;
#pragma unroll
        for (int r = 0; r < 4; ++r) {
          float sv = s[i][j][r] * SC;
          if (domask) {
            const int qg = qt * 128 + w * 32 + i * 16 + quad * 4 + r;
            if (kg > qg) sv = -1e30f;
          }
          s[i][j][r] = sv;
          mx[r] = fmaxf(mx[r], sv);
        }
      }
#pragma unroll
      for (int r = 0; r < 4; ++r) {
        mx[r] = fmaxf(mx[r], __shfl_xor(mx[r], 1));
        mx[r] = fmaxf(mx[r], __shfl_xor(mx[r], 2));
        mx[r] = fmaxf(mx[r], __shfl_xor(mx[r], 4));
        mx[r] = fmaxf(mx[r], __shfl_xor(mx[r], 8));
        const float mnew = fmaxf(m_run[i][r], mx[r]);
        al[r] = exp2f(m_run[i][r] - mnew);
        m_run[i][r] = mnew;
      }
#pragma unroll
      for (int j = 0; j < 4; ++j) {
        const int colbase = (j * 16 + l15) ^ (8 * quad);  // swizzle key = 8*((row>>2)&3)
#pragma unroll
        for (int r = 0; r < 4; ++r) {
          const float pv = exp2f(s[i][j][r] - m_run[i][r]);
          Psw[(i * 16 + quad * 4 + r) * 72 + colbase] = f2bf(pv);
        }
      }
#pragma unroll
      for (int r = 0; r < 4; ++r) {
        accL[i][r] *= al[r];
#pragma unroll
        for (int jd = 0; jd < 4; ++jd) accO[i][jd][r] *= al[r];
      }
    }
    asm volatile("s_waitcnt lgkmcnt(0)" ::: "memory");  // wave-local P writes -> reads

    // ---- O += P V ; l += P . 1  ----
    const unsigned short* Vt = LDS_V(cur);
#pragma unroll
    for (int ks = 0; ks < 2; ++ks) {
      short8 pf[2];
#pragma unroll
      for (int i = 0; i < 2; ++i)
        pf[i] = *(const short8*)(Psw + (i * 16 + l15) * 72 +
                                 ((ks * 32 + quad * 8) ^ (8 * ((l15 >> 2) & 3))));
      accL[0] = __builtin_amdgcn_mfma_f32_16x16x32_bf16(pf[0], ones, accL[0], 0, 0, 0);
      accL[1] = __builtin_amdgcn_mfma_f32_16x16x32_bf16(pf[1], ones, accL[1], 0, 0, 0);
#pragma unroll
      for (int jd = 0; jd < 4; ++jd) {
        const int d = jd * 16 + l15;
        const short8 vf = *(const short8*)(Vt + d * 72 +
                                           ((ks * 32 + quad * 8) ^ (8 * ((d >> 3) & 7))));
        accO[0][jd] = __builtin_amdgcn_mfma_f32_16x16x32_bf16(pf[0], vf, accO[0][jd], 0, 0, 0);
        accO[1][jd] = __builtin_amdgcn_mfma_f32_16x16x32_bf16(pf[1], vf, accO[1][jd], 0, 0, 0);
      }
    }

    // ---- write next V tile (regs -> LDS, swizzled) ----
    if (kt < ktmax) {
      unsigned short* Vtn = LDS_V(nxt);
      const unsigned short* s0 = (const unsigned short*)&v0;
      const unsigned short* s1 = (const unsigned short*)&v1;
#pragma unroll
      for (int e = 0; e < 8; ++e) {
        Vtn[(vd + e) * 72 + (vr ^ vkey)] = s0[e];
        Vtn[(vd + e) * 72 + ((vr + 32) ^ vkey)] = s1[e];
      }
    }
    __syncthreads();  // drains K(kt+1) async loads + V writes; all hidden behind compute
  }

  // ---- epilogue: O / l -> attn [4096, 2048] bf16 ----
#pragma unroll
  for (int i = 0; i < 2; ++i) {
#pragma unroll
    for (int jd = 0; jd < 4; ++jd) {
      const int col = h * 64 + jd * 16 + l15;
#pragma unroll
      for (int r = 0; r < 4; ++r) {
        const size_t row = rowQ + w * 32 + i * 16 + quad * 4 + r;
        attn[row * TC + col] = f2bf(accO[i][jd][r] / accL[i][r]);
      }
    }
  }
}

// ---------- launch ----------
extern "C" void kernel_launch(void* const* d_in, const int* in_sizes, int n_in,
                              void* d_out, int out_size, void* d_ws, size_t ws_size,
                              hipStream_t stream) {
  const float* x = (const float*)d_in[0];
  const float* Wq = (const float*)d_in[1];
  const float* Wk = (const float*)d_in[2];
  const float* Wv = (const float*)d_in[3];
  const float* Wo = (const float*)d_in[4];
  float* out = (float*)d_out;

  char* ws = (char*)d_ws;
  unsigned short* xb   = (unsigned short*)(ws);                       // 4096x2048 bf16
  unsigned short* wqkv = (unsigned short*)(ws + 16777216);            // 3072x2048 bf16
  unsigned short* wob  = (unsigned short*)(ws + 16777216 + 12582912); // 2048x2048 bf16
  unsigned short* qkv  = (unsigned short*)(ws + 37748736);            // 4096x3072 bf16
  unsigned short* attn = (unsigned short*)(ws + 62914560);            // 4096x2048 bf16
  // total ws use: 79,691,776 bytes

  cast_all<<<18432, 256, 0, stream>>>(x, Wq, Wk, Wv, Wo, xb, wqkv, wob);
  gemm_nt<unsigned short><<<dim3(QKVN / 128, 4096 / 128), 256, 0, stream>>>(
      xb, wqkv, qkv, 4096, QKVN, 2048);
  rope_kernel<<<20480, 256, 0, stream>>>(qkv);
  attn_kernel<<<dim3(16, 32, 2), 256, 0, stream>>>(qkv, attn);
  gemm_nt<float><<<dim3(TC / 128, 4096 / 128), 256, 0, stream>>>(
      attn, wob, out, 4096, TC, 2048);
}

// Round 3
// 363.616 us; speedup vs baseline: 1.5777x; 1.4393x over previous
//
#include <hip/hip_runtime.h>
#include <hip/hip_bf16.h>
#include <math.h>

// ---------- types / helpers ----------
typedef short short8 __attribute__((ext_vector_type(8)));
typedef float floatx4 __attribute__((ext_vector_type(4)));

typedef __attribute__((address_space(1))) unsigned int as1_u32;
typedef __attribute__((address_space(3))) unsigned int as3_u32;

__device__ __forceinline__ void load_lds16(const void* g, void* l) {
  // async 16B/lane global->LDS; HW dest = wave-uniform base + lane*16
  __builtin_amdgcn_global_load_lds((const as1_u32*)g, (as3_u32*)l, 16, 0, 0);
}

__device__ __forceinline__ unsigned short f2bf(float f) {
  __bf16 h = (__bf16)f;
  return __builtin_bit_cast(unsigned short, h);
}
__device__ __forceinline__ float bf2f(unsigned short u) {
  unsigned int x = ((unsigned int)u) << 16;
  return __builtin_bit_cast(float, x);
}

// ---------- constants ----------
#define TB 2
#define TT 2048
#define TC 2048
#define TH 32
#define THKV 8
#define TD 64
#define QKVN 3072   // 2048 Q + 512 K + 512 V
#define KOFF 2048
#define VOFF 2560

// ---------- 0: cast fp32 -> bf16 (x, packed Wqkv, Wo) ----------
__global__ __launch_bounds__(256) void cast_all(
    const float* __restrict__ x, const float* __restrict__ wq,
    const float* __restrict__ wk, const float* __restrict__ wv,
    const float* __restrict__ wo,
    unsigned short* __restrict__ xb, unsigned short* __restrict__ wqkv,
    unsigned short* __restrict__ wob) {
  long i4 = (long)blockIdx.x * 256 + threadIdx.x;  // float4 index
  const float* src;
  unsigned short* dst;
  if (i4 < 2097152)      { src = x;  dst = xb; }
  else if (i4 < 3145728) { src = wq; dst = wqkv;           i4 -= 2097152; }
  else if (i4 < 3407872) { src = wk; dst = wqkv + 4194304; i4 -= 3145728; }
  else if (i4 < 3670016) { src = wv; dst = wqkv + 5242880; i4 -= 3407872; }
  else                   { src = wo; dst = wob;            i4 -= 3670016; }
  float4 v = ((const float4*)src)[i4];
  ushort4 o;
  o.x = f2bf(v.x); o.y = f2bf(v.y); o.z = f2bf(v.z); o.w = f2bf(v.w);
  ((ushort4*)dst)[i4] = o;
}

// ---------- 1: NT GEMM  C[M,N] = A[M,K] * B[N,K]^T  (bf16 in, fp32 acc) ----------
// LDS staging is XOR-swizzled: LDS[row][g] = A[row][g ^ (row&7)] (g = 8-elem group)
__device__ __forceinline__ void store_val(float* p, float v) { *p = v; }
__device__ __forceinline__ void store_val(unsigned short* p, float v) { *p = f2bf(v); }

template <typename OutT>
__global__ __launch_bounds__(256) void gemm_nt(const unsigned short* __restrict__ A,
                                               const unsigned short* __restrict__ Bw,
                                               OutT* __restrict__ C,
                                               int M, int N, int K) {
  __shared__ unsigned short As[128 * 64];
  __shared__ unsigned short Bs[128 * 64];
  const int tid = threadIdx.x;
  const int lane = tid & 63, w = tid >> 6;
  const int quad = lane >> 4, l15 = lane & 15;
  const int wm = w >> 1, wn = w & 1;
  const int m0 = blockIdx.y * 128, n0 = blockIdx.x * 128;

  floatx4 acc[4][4];
#pragma unroll
  for (int i = 0; i < 4; ++i)
#pragma unroll
    for (int j = 0; j < 4; ++j) acc[i][j] = (floatx4){0.f, 0.f, 0.f, 0.f};

  const int ar = tid >> 3;                          // staging row (0..31 per pass)
  const int ac = (((tid & 7) ^ (ar & 7)) * 8);      // swizzled col-group
  const unsigned short* Abase = A + (size_t)(m0 + ar) * K + ac;
  const unsigned short* Bbase = Bw + (size_t)(n0 + ar) * K + ac;

  for (int k0 = 0; k0 < K; k0 += 64) {
    __syncthreads();
#pragma unroll
    for (int p = 0; p < 4; ++p) {
      load_lds16(Abase + (size_t)(p * 32) * K + k0, (char*)As + p * 4096 + tid * 16);
      load_lds16(Bbase + (size_t)(p * 32) * K + k0, (char*)Bs + p * 4096 + tid * 16);
    }
    __syncthreads();
#pragma unroll
    for (int ks = 0; ks < 2; ++ks) {
      short8 af[4], bfr[4];
      const int key = (((ks << 2) + quad) ^ (l15 & 7)) << 4;
#pragma unroll
      for (int i = 0; i < 4; ++i)
        af[i] = *(const short8*)((const char*)As + (wm * 64 + i * 16 + l15) * 128 + key);
#pragma unroll
      for (int j = 0; j < 4; ++j)
        bfr[j] = *(const short8*)((const char*)Bs + (wn * 64 + j * 16 + l15) * 128 + key);
#pragma unroll
      for (int i = 0; i < 4; ++i)
#pragma unroll
        for (int j = 0; j < 4; ++j)
          acc[i][j] = __builtin_amdgcn_mfma_f32_16x16x32_bf16(af[i], bfr[j], acc[i][j], 0, 0, 0);
    }
  }
  // epilogue: C/D layout col=lane&15, row=quad*4+reg (m89-verified)
#pragma unroll
  for (int i = 0; i < 4; ++i) {
    const int row = m0 + wm * 64 + i * 16 + quad * 4;
#pragma unroll
    for (int j = 0; j < 4; ++j) {
      const int col = n0 + wn * 64 + j * 16 + l15;
#pragma unroll
      for (int r = 0; r < 4; ++r)
        store_val(C + (size_t)(row + r) * N + col, acc[i][j][r]);
    }
  }
}

// ---------- 2: RoPE in-place on Q and K halves of qkv [4096, 3072] bf16 ----------
__global__ __launch_bounds__(256) void rope_kernel(unsigned short* __restrict__ qkv) {
  const int idx = blockIdx.x * 256 + threadIdx.x;  // < 4096*1280
  const int row = idx / 1280;
  const int p = idx - row * 1280;
  const int t = row & (TT - 1);
  int col, d;
  if (p < 1024) { d = p & 31; col = (p >> 5) * 64 + d; }
  else { const int p2 = p - 1024; d = p2 & 31; col = KOFF + (p2 >> 5) * 64 + d; }
  const size_t base = (size_t)row * QKVN + col;
  const float a = bf2f(qkv[base]);
  const float b = bf2f(qkv[base + 32]);
  const float inv = powf(10000.f, -(float)d * (1.f / 32.f));
  float sn, cs;
  sincosf((float)t * inv, &sn, &cs);
  qkv[base]      = f2bf(a * cs - b * sn);
  qkv[base + 32] = f2bf(b * cs + a * sn);
}

// ---------- 2b: transpose V -> vT [512 d][4096 (b*T+t)] ----------
__global__ __launch_bounds__(256) void vtrans(const unsigned short* __restrict__ qkv,
                                              unsigned short* __restrict__ vT) {
  __shared__ unsigned short tle[64 * 80];
  const int tt = blockIdx.x, dt = blockIdx.y, b = blockIdx.z;
  const int tid = threadIdx.x;
  const int r = tid >> 3, g = tid & 7;
#pragma unroll
  for (int p = 0; p < 2; ++p) {
    const int tl = p * 32 + r;
    uint4 v = *(const uint4*)(qkv + (size_t)(b * TT + tt * 64 + tl) * QKVN + VOFF + dt * 64 + g * 8);
    const unsigned short* s = (const unsigned short*)&v;
#pragma unroll
    for (int e = 0; e < 8; ++e) tle[(g * 8 + e) * 80 + tl] = s[e];
  }
  __syncthreads();
#pragma unroll
  for (int p = 0; p < 2; ++p) {
    const int dl = p * 32 + r;
    uint4 o = *(const uint4*)(tle + dl * 80 + g * 8);
    *(uint4*)(vT + (size_t)(dt * 64 + dl) * 4096 + b * TT + tt * 64 + g * 8) = o;
  }
}

// ---------- 3: causal flash attention v3 ----------
// grid (8, 32, 2); each block does q-tile pair (bx, 15-bx) -> constant 34 kv-tiles.
// S^T formulation (A=K, B=Q) -> vectorized P round-trip; V pre-transposed in global.
// LDS: K[2] 2x8192 | V[2] 2x8192 | P 4x4608  = 51200 B
#define LDSA_K(buf) (lds + (buf) * 8192)
#define LDSA_V(buf) (lds + 16384 + (buf) * 8192)
#define LDSA_P      (lds + 32768)

__global__ __launch_bounds__(256) void attn_kernel(const unsigned short* __restrict__ qkv,
                                                   const unsigned short* __restrict__ vT,
                                                   unsigned short* __restrict__ attn) {
  const int bx = blockIdx.x;  // 0..7
  const int h = blockIdx.y, b = blockIdx.z;
  const int hk = h >> 2;
  const int tid = threadIdx.x;
  const int w = tid >> 6, lane = tid & 63, quad = lane >> 4, l15 = lane & 15;

  __shared__ char lds[51200];
  unsigned short* Pq = (unsigned short*)(LDSA_P + w * 4608);  // [32 q][72 kk]

  const int srow = tid >> 3;                    // staging row
  const int sgrp = ((tid & 7) ^ (srow & 7));    // swizzled source col-group

  for (int pass = 0; pass < 2; ++pass) {
    const int qt = pass ? (15 - bx) : bx;
    const size_t rowQ = (size_t)(b * TT + qt * 128);

    // ---- stage Q tile (128x64, swizzled) into K(0)+K(1) region ----
    {
      const unsigned short* qsrc = qkv + (rowQ + srow) * QKVN + h * 64 + sgrp * 8;
#pragma unroll
      for (int p = 0; p < 4; ++p)
        load_lds16(qsrc + (size_t)p * 32 * QKVN, lds + p * 4096 + tid * 16);
    }
    __syncthreads();
    short8 qf[2][2];  // B-operand frags: Q[q=l15(+i*16)][d=ks*32+quad*8..]
#pragma unroll
    for (int i = 0; i < 2; ++i)
#pragma unroll
      for (int ks = 0; ks < 2; ++ks)
        qf[i][ks] = *(const short8*)(lds + (w * 32 + i * 16 + l15) * 128 +
                                     ((((ks << 2) + quad) ^ (l15 & 7)) << 4));
    __syncthreads();  // all waves done reading Q before K(0) overwrites

    floatx4 accO[2][4];
    float m_run[2], l_run[2];
#pragma unroll
    for (int i = 0; i < 2; ++i) {
      m_run[i] = -1e30f; l_run[i] = 0.f;
#pragma unroll
      for (int j = 0; j < 4; ++j) accO[i][j] = (floatx4){0.f, 0.f, 0.f, 0.f};
    }

    // ---- prologue: stage tile 0 (K + V, both async, swizzled) ----
    {
      const unsigned short* ksrc =
          qkv + (size_t)(b * TT + srow) * QKVN + KOFF + hk * 64 + sgrp * 8;
      load_lds16(ksrc, LDSA_K(0) + tid * 16);
      load_lds16(ksrc + (size_t)32 * QKVN, LDSA_K(0) + 4096 + tid * 16);
      const unsigned short* vsrc =
          vT + (size_t)(hk * 64 + srow) * 4096 + b * TT + sgrp * 8;
      load_lds16(vsrc, LDSA_V(0) + tid * 16);
      load_lds16(vsrc + (size_t)32 * 4096, LDSA_V(0) + 4096 + tid * 16);
    }
    __syncthreads();

    const int ktmax = 2 * qt + 1;
    for (int kt = 0; kt <= ktmax; ++kt) {
      const int cur = kt & 1, nxt = cur ^ 1;
      // ---- prefetch next tile (async; drained by end-of-iter barrier) ----
      if (kt < ktmax) {
        const unsigned short* ksrc =
            qkv + (size_t)(b * TT + (kt + 1) * 64 + srow) * QKVN + KOFF + hk * 64 + sgrp * 8;
        load_lds16(ksrc, LDSA_K(nxt) + tid * 16);
        load_lds16(ksrc + (size_t)32 * QKVN, LDSA_K(nxt) + 4096 + tid * 16);
        const unsigned short* vsrc =
            vT + (size_t)(hk * 64 + srow) * 4096 + b * TT + (kt + 1) * 64 + sgrp * 8;
        load_lds16(vsrc, LDSA_V(nxt) + tid * 16);
        load_lds16(vsrc + (size_t)32 * 4096, LDSA_V(nxt) + 4096 + tid * 16);
      }

      // ---- S^T = K Q^T : D[kk_local][q_local] ----
      const char* Ks = LDSA_K(cur);
      floatx4 st[2][4];  // [i=q-tile][jm=kk-tile]
#pragma unroll
      for (int jm = 0; jm < 4; ++jm) {
        const int krow = jm * 16 + l15;
        const short8 kf0 = *(const short8*)(Ks + krow * 128 + ((quad ^ (l15 & 7)) << 4));
        const short8 kf1 = *(const short8*)(Ks + krow * 128 + (((4 + quad) ^ (l15 & 7)) << 4));
#pragma unroll
        for (int i = 0; i < 2; ++i) {
          floatx4 z = (floatx4){0.f, 0.f, 0.f, 0.f};
          z = __builtin_amdgcn_mfma_f32_16x16x32_bf16(kf0, qf[i][0], z, 0, 0, 0);
          st[i][jm] = __builtin_amdgcn_mfma_f32_16x16x32_bf16(kf1, qf[i][1], z, 0, 0, 0);
        }
      }

      // ---- online softmax (exp2 domain), P -> LDS q-major (vectorized b64) ----
      const bool domask = (kt >= 2 * qt);
      const float SC = 0.18033688f;  // (1/8) * log2(e)
      float alq[2];
#pragma unroll
      for (int i = 0; i < 2; ++i) {
        const int qg = qt * 128 + w * 32 + i * 16 + l15;  // this lane's q (column)
        float mx = -1e30f;
#pragma unroll
        for (int jm = 0; jm < 4; ++jm) {
#pragma unroll
          for (int r = 0; r < 4; ++r) {
            float sv = st[i][jm][r] * SC;
            if (domask) {
              const int kg = kt * 64 + jm * 16 + quad * 4 + r;
              if (kg > qg) sv = -1e30f;
            }
            st[i][jm][r] = sv;
            mx = fmaxf(mx, sv);
          }
        }
        mx = fmaxf(mx, __shfl_xor(mx, 16));
        mx = fmaxf(mx, __shfl_xor(mx, 32));
        const float mnew = fmaxf(m_run[i], mx);
        alq[i] = exp2f(m_run[i] - mnew);
        m_run[i] = mnew;
        float rs = 0.f;
#pragma unroll
        for (int jm = 0; jm < 4; ++jm) {
          const float e0 = exp2f(st[i][jm][0] - mnew);
          const float e1 = exp2f(st[i][jm][1] - mnew);
          const float e2 = exp2f(st[i][jm][2] - mnew);
          const float e3 = exp2f(st[i][jm][3] - mnew);
          rs += (e0 + e1) + (e2 + e3);
          ushort4 pk;
          pk.x = f2bf(e0); pk.y = f2bf(e1); pk.z = f2bf(e2); pk.w = f2bf(e3);
          *(ushort4*)(Pq + (i * 16 + l15) * 72 + jm * 16 + quad * 4) = pk;
        }
        rs += __shfl_xor(rs, 16);
        rs += __shfl_xor(rs, 32);
        l_run[i] = l_run[i] * alq[i] + rs;
      }
      // rescale accO: al broadcast from lane (quad*4+r) to C-layout rows
#pragma unroll
      for (int i2 = 0; i2 < 2; ++i2)
#pragma unroll
        for (int r = 0; r < 4; ++r) {
          const float alb = __shfl(alq[i2], quad * 4 + r);
#pragma unroll
          for (int jd = 0; jd < 4; ++jd) accO[i2][jd][r] *= alb;
        }
      asm volatile("s_waitcnt lgkmcnt(0)" ::: "memory");  // wave-local P writes -> reads

      // ---- O += P V  (A=P from Pq, B=V^T from swizzled V tile) ----
      const char* Vt = LDSA_V(cur);
#pragma unroll
      for (int ks = 0; ks < 2; ++ks) {
        short8 pf[2];
#pragma unroll
        for (int i2 = 0; i2 < 2; ++i2)
          pf[i2] = *(const short8*)(Pq + (i2 * 16 + l15) * 72 + ks * 32 + quad * 8);
#pragma unroll
        for (int jd = 0; jd < 4; ++jd) {
          const int d = jd * 16 + l15;
          const short8 vf = *(const short8*)(Vt + d * 128 +
                                             ((((ks << 2) + quad) ^ (l15 & 7)) << 4));
          accO[0][jd] = __builtin_amdgcn_mfma_f32_16x16x32_bf16(pf[0], vf, accO[0][jd], 0, 0, 0);
          accO[1][jd] = __builtin_amdgcn_mfma_f32_16x16x32_bf16(pf[1], vf, accO[1][jd], 0, 0, 0);
        }
      }
      __syncthreads();  // drains prefetch + protects cur-buffer overwrite next iter
    }

    // ---- epilogue: O / l -> attn ----
#pragma unroll
    for (int i2 = 0; i2 < 2; ++i2) {
      float lr[4];
#pragma unroll
      for (int r = 0; r < 4; ++r) lr[r] = __shfl(l_run[i2], quad * 4 + r);
#pragma unroll
      for (int jd = 0; jd < 4; ++jd) {
        const int col = h * 64 + jd * 16 + l15;
#pragma unroll
        for (int r = 0; r < 4; ++r) {
          const size_t row = rowQ + w * 32 + i2 * 16 + quad * 4 + r;
          attn[row * TC + col] = f2bf(accO[i2][jd][r] / lr[r]);
        }
      }
    }
  }
}

// ---------- launch ----------
extern "C" void kernel_launch(void* const* d_in, const int* in_sizes, int n_in,
                              void* d_out, int out_size, void* d_ws, size_t ws_size,
                              hipStream_t stream) {
  const float* x = (const float*)d_in[0];
  const float* Wq = (const float*)d_in[1];
  const float* Wk = (const float*)d_in[2];
  const float* Wv = (const float*)d_in[3];
  const float* Wo = (const float*)d_in[4];
  float* out = (float*)d_out;

  char* ws = (char*)d_ws;
  unsigned short* xb   = (unsigned short*)(ws);                       // 4096x2048 bf16 (dead after gemm1)
  unsigned short* vT   = (unsigned short*)(ws);                       // 512x4096 bf16 (aliases xb)
  unsigned short* wqkv = (unsigned short*)(ws + 16777216);            // 3072x2048 bf16
  unsigned short* wob  = (unsigned short*)(ws + 16777216 + 12582912); // 2048x2048 bf16
  unsigned short* qkv  = (unsigned short*)(ws + 37748736);            // 4096x3072 bf16
  unsigned short* attn = (unsigned short*)(ws + 62914560);            // 4096x2048 bf16
  // total ws use: 79,691,776 bytes

  cast_all<<<18432, 256, 0, stream>>>(x, Wq, Wk, Wv, Wo, xb, wqkv, wob);
  gemm_nt<unsigned short><<<dim3(QKVN / 128, 4096 / 128), 256, 0, stream>>>(
      xb, wqkv, qkv, 4096, QKVN, 2048);
  rope_kernel<<<20480, 256, 0, stream>>>(qkv);
  vtrans<<<dim3(32, 8, 2), 256, 0, stream>>>(qkv, vT);
  attn_kernel<<<dim3(8, 32, 2), 256, 0, stream>>>(qkv, vT, attn);
  gemm_nt<float><<<dim3(TC / 128, 4096 / 128), 256, 0, stream>>>(
      attn, wob, out, 4096, TC, 2048);
}

// Round 4
// 300.826 us; speedup vs baseline: 1.9071x; 1.2087x over previous
//
#include <hip/hip_runtime.h>
#include <hip/hip_bf16.h>
#include <math.h>

// ---------- types / helpers ----------
typedef short short8 __attribute__((ext_vector_type(8)));
typedef float floatx4 __attribute__((ext_vector_type(4)));

typedef __attribute__((address_space(1))) unsigned int as1_u32;
typedef __attribute__((address_space(3))) unsigned int as3_u32;

__device__ __forceinline__ void load_lds16(const void* g, void* l) {
  // async 16B/lane global->LDS; HW dest = wave-uniform base + lane*16
  __builtin_amdgcn_global_load_lds((const as1_u32*)g, (as3_u32*)l, 16, 0, 0);
}

__device__ __forceinline__ unsigned short f2bf(float f) {
  __bf16 h = (__bf16)f;
  return __builtin_bit_cast(unsigned short, h);
}

// ---------- constants ----------
#define TB 2
#define TT 2048
#define TC 2048
#define QKN 2560    // qk row stride: 2048 Q + 512 K
#define KOFF 2048
#define SCALE_Q 0.18033688f  // (1/8) * log2(e), folded into Q at projection

// ---------- 0: cast fp32 -> bf16 (x, packed Wqkv, Wo) ----------
__global__ __launch_bounds__(256) void cast_all(
    const float* __restrict__ x, const float* __restrict__ wq,
    const float* __restrict__ wk, const float* __restrict__ wv,
    const float* __restrict__ wo,
    unsigned short* __restrict__ xb, unsigned short* __restrict__ wqkv,
    unsigned short* __restrict__ wob) {
  long i4 = (long)blockIdx.x * 256 + threadIdx.x;  // float4 index
  const float* src;
  unsigned short* dst;
  if (i4 < 2097152)      { src = x;  dst = xb; }
  else if (i4 < 3145728) { src = wq; dst = wqkv;           i4 -= 2097152; }
  else if (i4 < 3407872) { src = wk; dst = wqkv + 4194304; i4 -= 3145728; }
  else if (i4 < 3670016) { src = wv; dst = wqkv + 5242880; i4 -= 3407872; }
  else                   { src = wo; dst = wob;            i4 -= 3670016; }
  float4 v = ((const float4*)src)[i4];
  ushort4 o;
  o.x = f2bf(v.x); o.y = f2bf(v.y); o.z = f2bf(v.z); o.w = f2bf(v.w);
  ((ushort4*)dst)[i4] = o;
}

// ---------- 1: QKV GEMM with fused RoPE + Q-scale + V-transpose epilogue ----------
// C[M=4096, N=3072] = xb * wqkv^T.  Q cols [0,2048): rope+scale -> qk;
// K cols [2048,2560): rope -> qk; V cols [2560,3072): transposed -> vT[512][4096].
__global__ __launch_bounds__(256) void gemm_qkv(const unsigned short* __restrict__ A,
                                                const unsigned short* __restrict__ Bw,
                                                unsigned short* __restrict__ qk,
                                                unsigned short* __restrict__ vT) {
  __shared__ unsigned short As[128 * 64];
  __shared__ unsigned short Bs[128 * 64];
  const int K = 2048;
  const int tid = threadIdx.x;
  const int lane = tid & 63, w = tid >> 6;
  const int quad = lane >> 4, l15 = lane & 15;
  const int wm = w >> 1, wn = w & 1;
  const int m0 = blockIdx.y * 128, n0 = blockIdx.x * 128;

  floatx4 acc[4][4];
#pragma unroll
  for (int i = 0; i < 4; ++i)
#pragma unroll
    for (int j = 0; j < 4; ++j) acc[i][j] = (floatx4){0.f, 0.f, 0.f, 0.f};

  const int ar = tid >> 3;
  const int ac = (((tid & 7) ^ (ar & 7)) * 8);  // swizzled col-group
  const unsigned short* Abase = A + (size_t)(m0 + ar) * K + ac;
  const unsigned short* Bbase = Bw + (size_t)(n0 + ar) * K + ac;

  for (int k0 = 0; k0 < K; k0 += 64) {
    __syncthreads();
#pragma unroll
    for (int p = 0; p < 4; ++p) {
      load_lds16(Abase + (size_t)(p * 32) * K + k0, (char*)As + p * 4096 + tid * 16);
      load_lds16(Bbase + (size_t)(p * 32) * K + k0, (char*)Bs + p * 4096 + tid * 16);
    }
    __syncthreads();
#pragma unroll
    for (int ks = 0; ks < 2; ++ks) {
      short8 af[4], bfr[4];
      const int key = (((ks << 2) + quad) ^ (l15 & 7)) << 4;
#pragma unroll
      for (int i = 0; i < 4; ++i)
        af[i] = *(const short8*)((const char*)As + (wm * 64 + i * 16 + l15) * 128 + key);
#pragma unroll
      for (int j = 0; j < 4; ++j)
        bfr[j] = *(const short8*)((const char*)Bs + (wn * 64 + j * 16 + l15) * 128 + key);
#pragma unroll
      for (int i = 0; i < 4; ++i)
#pragma unroll
        for (int j = 0; j < 4; ++j)
          acc[i][j] = __builtin_amdgcn_mfma_f32_16x16x32_bf16(af[i], bfr[j], acc[i][j], 0, 0, 0);
    }
  }

  const int colb = n0 + wn * 64;  // wave-uniform region selector (64-aligned)
  if (colb < QKN) {
    // ---- Q or K: RoPE on fp32 acc, optional scale, store to qk (stride 2560) ----
    const float qscale = (colb < KOFF) ? SCALE_Q : 1.0f;
#pragma unroll
    for (int i = 0; i < 4; ++i) {
      const int rowb = m0 + wm * 64 + i * 16 + quad * 4;
      const int tb = rowb & (TT - 1);
#pragma unroll
      for (int j = 0; j < 2; ++j) {
        const int col = colb + j * 16 + l15;
        const int d = j * 16 + l15;  // 0..31
        const float inv = exp2f((float)d * -0.4152410119f);  // 10000^(-d/32)
#pragma unroll
        for (int r = 0; r < 4; ++r) {
          float sn, cs;
          sincosf((float)(tb + r) * inv, &sn, &cs);
          const float a = acc[i][j][r], b2 = acc[i][j + 2][r];
          const float qa = (a * cs - b2 * sn) * qscale;
          const float qb = (b2 * cs + a * sn) * qscale;
          unsigned short* p = qk + (size_t)(rowb + r) * QKN + col;
          p[0] = f2bf(qa);
          p[32] = f2bf(qb);
        }
      }
    }
  } else {
    // ---- V: transposed packed store  vT[col-2560][rowb..rowb+3] ----
#pragma unroll
    for (int i = 0; i < 4; ++i) {
      const int rowb = m0 + wm * 64 + i * 16 + quad * 4;
#pragma unroll
      for (int j = 0; j < 4; ++j) {
        const int col = colb + j * 16 + l15;
        ushort4 pk;
        pk.x = f2bf(acc[i][j][0]); pk.y = f2bf(acc[i][j][1]);
        pk.z = f2bf(acc[i][j][2]); pk.w = f2bf(acc[i][j][3]);
        *(ushort4*)(vT + (size_t)(col - 2560) * 4096 + rowb) = pk;
      }
    }
  }
}

// ---------- 1b: generic NT GEMM (for output projection, f32 out) ----------
__global__ __launch_bounds__(256) void gemm_nt_f32(const unsigned short* __restrict__ A,
                                                   const unsigned short* __restrict__ Bw,
                                                   float* __restrict__ C,
                                                   int M, int N, int K) {
  __shared__ unsigned short As[128 * 64];
  __shared__ unsigned short Bs[128 * 64];
  const int tid = threadIdx.x;
  const int lane = tid & 63, w = tid >> 6;
  const int quad = lane >> 4, l15 = lane & 15;
  const int wm = w >> 1, wn = w & 1;
  const int m0 = blockIdx.y * 128, n0 = blockIdx.x * 128;

  floatx4 acc[4][4];
#pragma unroll
  for (int i = 0; i < 4; ++i)
#pragma unroll
    for (int j = 0; j < 4; ++j) acc[i][j] = (floatx4){0.f, 0.f, 0.f, 0.f};

  const int ar = tid >> 3;
  const int ac = (((tid & 7) ^ (ar & 7)) * 8);
  const unsigned short* Abase = A + (size_t)(m0 + ar) * K + ac;
  const unsigned short* Bbase = Bw + (size_t)(n0 + ar) * K + ac;

  for (int k0 = 0; k0 < K; k0 += 64) {
    __syncthreads();
#pragma unroll
    for (int p = 0; p < 4; ++p) {
      load_lds16(Abase + (size_t)(p * 32) * K + k0, (char*)As + p * 4096 + tid * 16);
      load_lds16(Bbase + (size_t)(p * 32) * K + k0, (char*)Bs + p * 4096 + tid * 16);
    }
    __syncthreads();
#pragma unroll
    for (int ks = 0; ks < 2; ++ks) {
      short8 af[4], bfr[4];
      const int key = (((ks << 2) + quad) ^ (l15 & 7)) << 4;
#pragma unroll
      for (int i = 0; i < 4; ++i)
        af[i] = *(const short8*)((const char*)As + (wm * 64 + i * 16 + l15) * 128 + key);
#pragma unroll
      for (int j = 0; j < 4; ++j)
        bfr[j] = *(const short8*)((const char*)Bs + (wn * 64 + j * 16 + l15) * 128 + key);
#pragma unroll
      for (int i = 0; i < 4; ++i)
#pragma unroll
        for (int j = 0; j < 4; ++j)
          acc[i][j] = __builtin_amdgcn_mfma_f32_16x16x32_bf16(af[i], bfr[j], acc[i][j], 0, 0, 0);
    }
  }
#pragma unroll
  for (int i = 0; i < 4; ++i) {
    const int row = m0 + wm * 64 + i * 16 + quad * 4;
#pragma unroll
    for (int j = 0; j < 4; ++j) {
      const int col = n0 + wn * 64 + j * 16 + l15;
#pragma unroll
      for (int r = 0; r < 4; ++r)
        C[(size_t)(row + r) * N + col] = acc[i][j][r];
    }
  }
}

// ---------- 2: causal flash attention v4 (fixed-max softmax, l via ones-MFMA) ----------
// grid (8, 32, 2); block does q-tile pair (bx, 15-bx) -> constant 34 kv-tiles.
// LDS: K[2] 2x8192 | V[2] 2x8192 | P 4x4608  = 51200 B
#define LDSA_K(buf) (lds + (buf) * 8192)
#define LDSA_V(buf) (lds + 16384 + (buf) * 8192)
#define LDSA_P      (lds + 32768)

__global__ __launch_bounds__(256) void attn_kernel(const unsigned short* __restrict__ qk,
                                                   const unsigned short* __restrict__ vT,
                                                   unsigned short* __restrict__ attn) {
  const int bx = blockIdx.x;  // 0..7
  const int h = blockIdx.y, b = blockIdx.z;
  const int hk = h >> 2;
  const int tid = threadIdx.x;
  const int w = tid >> 6, lane = tid & 63, quad = lane >> 4, l15 = lane & 15;

  __shared__ char lds[51200];
  unsigned short* Pq = (unsigned short*)(LDSA_P + w * 4608);  // [32 q][72 kk]

  const int srow = tid >> 3;                    // staging row
  const int sgrp = ((tid & 7) ^ (srow & 7));    // swizzled source col-group

  const short8 ones = {16256, 16256, 16256, 16256, 16256, 16256, 16256, 16256};  // bf16 1.0

  for (int pass = 0; pass < 2; ++pass) {
    const int qt = pass ? (15 - bx) : bx;
    const size_t rowQ = (size_t)(b * TT + qt * 128);

    // ---- stage Q tile (128x64, swizzled) into K(0)+K(1) region ----
    {
      const unsigned short* qsrc = qk + (rowQ + srow) * QKN + h * 64 + sgrp * 8;
#pragma unroll
      for (int p = 0; p < 4; ++p)
        load_lds16(qsrc + (size_t)p * 32 * QKN, lds + p * 4096 + tid * 16);
    }
    __syncthreads();
    short8 qf[2][2];  // B-operand frags: Q[q=l15(+i*16)][d=ks*32+quad*8..]
#pragma unroll
    for (int i = 0; i < 2; ++i)
#pragma unroll
      for (int ks = 0; ks < 2; ++ks)
        qf[i][ks] = *(const short8*)(lds + (w * 32 + i * 16 + l15) * 128 +
                                     ((((ks << 2) + quad) ^ (l15 & 7)) << 4));
    __syncthreads();  // all waves done reading Q before K(0) overwrites

    floatx4 accO[2][4], accL[2];
#pragma unroll
    for (int i = 0; i < 2; ++i) {
      accL[i] = (floatx4){0.f, 0.f, 0.f, 0.f};
#pragma unroll
      for (int j = 0; j < 4; ++j) accO[i][j] = (floatx4){0.f, 0.f, 0.f, 0.f};
    }

    // ---- prologue: stage tile 0 (K + V, async, swizzled) ----
    {
      const unsigned short* ksrc =
          qk + (size_t)(b * TT + srow) * QKN + KOFF + hk * 64 + sgrp * 8;
      load_lds16(ksrc, LDSA_K(0) + tid * 16);
      load_lds16(ksrc + (size_t)32 * QKN, LDSA_K(0) + 4096 + tid * 16);
      const unsigned short* vsrc =
          vT + (size_t)(hk * 64 + srow) * 4096 + b * TT + sgrp * 8;
      load_lds16(vsrc, LDSA_V(0) + tid * 16);
      load_lds16(vsrc + (size_t)32 * 4096, LDSA_V(0) + 4096 + tid * 16);
    }
    __syncthreads();

    const int ktmax = 2 * qt + 1;
    for (int kt = 0; kt <= ktmax; ++kt) {
      const int cur = kt & 1, nxt = cur ^ 1;
      // ---- prefetch next tile (async; drained by end-of-iter barrier) ----
      if (kt < ktmax) {
        const unsigned short* ksrc =
            qk + (size_t)(b * TT + (kt + 1) * 64 + srow) * QKN + KOFF + hk * 64 + sgrp * 8;
        load_lds16(ksrc, LDSA_K(nxt) + tid * 16);
        load_lds16(ksrc + (size_t)32 * QKN, LDSA_K(nxt) + 4096 + tid * 16);
        const unsigned short* vsrc =
            vT + (size_t)(hk * 64 + srow) * 4096 + b * TT + (kt + 1) * 64 + sgrp * 8;
        load_lds16(vsrc, LDSA_V(nxt) + tid * 16);
        load_lds16(vsrc + (size_t)32 * 4096, LDSA_V(nxt) + 4096 + tid * 16);
      }

      // ---- S^T = K Q^T : D[kk_local][q_local]  (scale pre-folded into Q) ----
      const char* Ks = LDSA_K(cur);
      floatx4 st[2][4];  // [i=q-tile][jm=kk-tile]
#pragma unroll
      for (int jm = 0; jm < 4; ++jm) {
        const int krow = jm * 16 + l15;
        const short8 kf0 = *(const short8*)(Ks + krow * 128 + ((quad ^ (l15 & 7)) << 4));
        const short8 kf1 = *(const short8*)(Ks + krow * 128 + (((4 + quad) ^ (l15 & 7)) << 4));
#pragma unroll
        for (int i = 0; i < 2; ++i) {
          floatx4 z = (floatx4){0.f, 0.f, 0.f, 0.f};
          z = __builtin_amdgcn_mfma_f32_16x16x32_bf16(kf0, qf[i][0], z, 0, 0, 0);
          st[i][jm] = __builtin_amdgcn_mfma_f32_16x16x32_bf16(kf1, qf[i][1], z, 0, 0, 0);
        }
      }

      // ---- fixed-max softmax: P = exp2(st), masked to 0; store q-major (b64) ----
      const bool domask = (kt >= 2 * qt);
#pragma unroll
      for (int i = 0; i < 2; ++i) {
        const int qg = qt * 128 + w * 32 + i * 16 + l15;  // this lane's q (column)
#pragma unroll
        for (int jm = 0; jm < 4; ++jm) {
          float e0 = exp2f(st[i][jm][0]);
          float e1 = exp2f(st[i][jm][1]);
          float e2 = exp2f(st[i][jm][2]);
          float e3 = exp2f(st[i][jm][3]);
          if (domask) {
            const int kg = kt * 64 + jm * 16 + quad * 4;
            if (kg > qg) e0 = 0.f;
            if (kg + 1 > qg) e1 = 0.f;
            if (kg + 2 > qg) e2 = 0.f;
            if (kg + 3 > qg) e3 = 0.f;
          }
          ushort4 pk;
          pk.x = f2bf(e0); pk.y = f2bf(e1); pk.z = f2bf(e2); pk.w = f2bf(e3);
          *(ushort4*)(Pq + (i * 16 + l15) * 72 + jm * 16 + quad * 4) = pk;
        }
      }
      asm volatile("s_waitcnt lgkmcnt(0)" ::: "memory");  // wave-local P writes -> reads

      // ---- O += P V ; l += P . 1  (A=P, B=V^T / ones) ----
      const char* Vt = LDSA_V(cur);
#pragma unroll
      for (int ks = 0; ks < 2; ++ks) {
        short8 pf[2];
#pragma unroll
        for (int i2 = 0; i2 < 2; ++i2)
          pf[i2] = *(const short8*)(Pq + (i2 * 16 + l15) * 72 + ks * 32 + quad * 8);
        accL[0] = __builtin_amdgcn_mfma_f32_16x16x32_bf16(pf[0], ones, accL[0], 0, 0, 0);
        accL[1] = __builtin_amdgcn_mfma_f32_16x16x32_bf16(pf[1], ones, accL[1], 0, 0, 0);
#pragma unroll
        for (int jd = 0; jd < 4; ++jd) {
          const int d = jd * 16 + l15;
          const short8 vf = *(const short8*)(Vt + d * 128 +
                                             ((((ks << 2) + quad) ^ (l15 & 7)) << 4));
          accO[0][jd] = __builtin_amdgcn_mfma_f32_16x16x32_bf16(pf[0], vf, accO[0][jd], 0, 0, 0);
          accO[1][jd] = __builtin_amdgcn_mfma_f32_16x16x32_bf16(pf[1], vf, accO[1][jd], 0, 0, 0);
        }
      }
      __syncthreads();  // drains prefetch + protects cur-buffer overwrite next iter
    }

    // ---- epilogue: O / l -> attn  (accL C-layout rows match accO rows) ----
#pragma unroll
    for (int i2 = 0; i2 < 2; ++i2) {
#pragma unroll
      for (int jd = 0; jd < 4; ++jd) {
        const int col = h * 64 + jd * 16 + l15;
#pragma unroll
        for (int r = 0; r < 4; ++r) {
          const size_t row = rowQ + w * 32 + i2 * 16 + quad * 4 + r;
          attn[row * TC + col] = f2bf(accO[i2][jd][r] / accL[i2][r]);
        }
      }
    }
  }
}

// ---------- launch ----------
extern "C" void kernel_launch(void* const* d_in, const int* in_sizes, int n_in,
                              void* d_out, int out_size, void* d_ws, size_t ws_size,
                              hipStream_t stream) {
  const float* x = (const float*)d_in[0];
  const float* Wq = (const float*)d_in[1];
  const float* Wk = (const float*)d_in[2];
  const float* Wv = (const float*)d_in[3];
  const float* Wo = (const float*)d_in[4];
  float* out = (float*)d_out;

  char* ws = (char*)d_ws;
  unsigned short* xb   = (unsigned short*)(ws);               // 4096x2048 bf16
  unsigned short* wqkv = (unsigned short*)(ws + 16777216);    // 3072x2048 bf16
  unsigned short* wob  = (unsigned short*)(ws + 29360128);    // 2048x2048 bf16
  unsigned short* qk   = (unsigned short*)(ws + 37748736);    // 4096x2560 bf16 (Q|K, roped)
  unsigned short* vT   = (unsigned short*)(ws + 58720256);    // 512x4096 bf16 (V transposed)
  unsigned short* attn = (unsigned short*)(ws + 62914560);    // 4096x2048 bf16
  // total ws use: 79,691,776 bytes (same as R3)

  cast_all<<<18432, 256, 0, stream>>>(x, Wq, Wk, Wv, Wo, xb, wqkv, wob);
  gemm_qkv<<<dim3(24, 32), 256, 0, stream>>>(xb, wqkv, qk, vT);
  attn_kernel<<<dim3(8, 32, 2), 256, 0, stream>>>(qk, vT, attn);
  gemm_nt_f32<<<dim3(16, 32), 256, 0, stream>>>(attn, wob, out, 4096, TC, 2048);
}

// Round 5
// 297.897 us; speedup vs baseline: 1.9258x; 1.0098x over previous
//
#include <hip/hip_runtime.h>
#include <hip/hip_bf16.h>
#include <math.h>

// ---------- types / helpers ----------
typedef short short8 __attribute__((ext_vector_type(8)));
typedef float floatx4 __attribute__((ext_vector_type(4)));

typedef __attribute__((address_space(1))) unsigned int as1_u32;
typedef __attribute__((address_space(3))) unsigned int as3_u32;

__device__ __forceinline__ void load_lds16(const void* g, void* l) {
  // async 16B/lane global->LDS; HW dest = wave-uniform base + lane*16
  __builtin_amdgcn_global_load_lds((const as1_u32*)g, (as3_u32*)l, 16, 0, 0);
}

__device__ __forceinline__ unsigned short f2bf(float f) {
  __bf16 h = (__bf16)f;
  return __builtin_bit_cast(unsigned short, h);
}

// ---------- constants ----------
#define TB 2
#define TT 2048
#define TC 2048
#define QKN 2560    // qk row stride: 2048 Q + 512 K
#define KOFF 2048
#define SCALE_Q 0.18033688f  // (1/8) * log2(e), folded into Q at projection

// ---------- 0: cast fp32 -> bf16 (x, packed Wqkv, Wo) + rope table ----------
__global__ __launch_bounds__(256) void cast_all(
    const float* __restrict__ x, const float* __restrict__ wq,
    const float* __restrict__ wk, const float* __restrict__ wv,
    const float* __restrict__ wo,
    unsigned short* __restrict__ xb, unsigned short* __restrict__ wqkv,
    unsigned short* __restrict__ wob, float2* __restrict__ ropeTab) {
  // rope table: 2048 t x 32 d (cos,sin) = 512 KB, built by first 256 blocks
  if (blockIdx.x < 256) {
    const int idx = blockIdx.x * 256 + threadIdx.x;  // t*32+d
    const int t = idx >> 5, d = idx & 31;
    const float inv = exp2f((float)d * -0.4152410119f);  // 10000^(-d/32)
    float sn, cs;
    sincosf((float)t * inv, &sn, &cs);
    ropeTab[idx] = make_float2(cs, sn);
  }
  long i4 = (long)blockIdx.x * 256 + threadIdx.x;  // float4 index
  const float* src;
  unsigned short* dst;
  if (i4 < 2097152)      { src = x;  dst = xb; }
  else if (i4 < 3145728) { src = wq; dst = wqkv;           i4 -= 2097152; }
  else if (i4 < 3407872) { src = wk; dst = wqkv + 4194304; i4 -= 3145728; }
  else if (i4 < 3670016) { src = wv; dst = wqkv + 5242880; i4 -= 3407872; }
  else                   { src = wo; dst = wob;            i4 -= 3670016; }
  float4 v = ((const float4*)src)[i4];
  ushort4 o;
  o.x = f2bf(v.x); o.y = f2bf(v.y); o.z = f2bf(v.z); o.w = f2bf(v.w);
  ((ushort4*)dst)[i4] = o;
}

// ---------- 1: QKV GEMM with fused RoPE + Q-scale + V-transpose epilogue ----------
// C[M=4096, N=3072] = xb * wqkv^T.  Q cols [0,2048): rope+scale -> qk;
// K cols [2048,2560): rope -> qk; V cols [2560,3072): transposed -> vT[512][4096].
// Block swizzle: XCD (lin&7) owns a 3-wide N-stripe -> B stays L2-resident.
__global__ __launch_bounds__(256) void gemm_qkv(const unsigned short* __restrict__ A,
                                                const unsigned short* __restrict__ Bw,
                                                unsigned short* __restrict__ qk,
                                                unsigned short* __restrict__ vT,
                                                const float2* __restrict__ ropeTab) {
  __shared__ unsigned short As[128 * 64];
  __shared__ unsigned short Bs[128 * 64];
  const int K = 2048;
  const int tid = threadIdx.x;
  const int lane = tid & 63, w = tid >> 6;
  const int quad = lane >> 4, l15 = lane & 15;
  const int wm = w >> 1, wn = w & 1;
  // XCD-aware swizzle: grid 24x32, lin&7 = XCD, each XCD owns cols [3k, 3k+3)
  const int lin = blockIdx.y * 24 + blockIdx.x;
  const int sub = lin >> 3;
  const int m0 = (sub / 3) * 128;
  const int n0 = ((lin & 7) * 3 + sub % 3) * 128;

  floatx4 acc[4][4];
#pragma unroll
  for (int i = 0; i < 4; ++i)
#pragma unroll
    for (int j = 0; j < 4; ++j) acc[i][j] = (floatx4){0.f, 0.f, 0.f, 0.f};

  const int ar = tid >> 3;
  const int ac = (((tid & 7) ^ (ar & 7)) * 8);  // swizzled col-group
  const unsigned short* Abase = A + (size_t)(m0 + ar) * K + ac;
  const unsigned short* Bbase = Bw + (size_t)(n0 + ar) * K + ac;

  for (int k0 = 0; k0 < K; k0 += 64) {
    __syncthreads();
#pragma unroll
    for (int p = 0; p < 4; ++p) {
      load_lds16(Abase + (size_t)(p * 32) * K + k0, (char*)As + p * 4096 + tid * 16);
      load_lds16(Bbase + (size_t)(p * 32) * K + k0, (char*)Bs + p * 4096 + tid * 16);
    }
    __syncthreads();
#pragma unroll
    for (int ks = 0; ks < 2; ++ks) {
      short8 af[4], bfr[4];
      const int key = (((ks << 2) + quad) ^ (l15 & 7)) << 4;
#pragma unroll
      for (int i = 0; i < 4; ++i)
        af[i] = *(const short8*)((const char*)As + (wm * 64 + i * 16 + l15) * 128 + key);
#pragma unroll
      for (int j = 0; j < 4; ++j)
        bfr[j] = *(const short8*)((const char*)Bs + (wn * 64 + j * 16 + l15) * 128 + key);
#pragma unroll
      for (int i = 0; i < 4; ++i)
#pragma unroll
        for (int j = 0; j < 4; ++j)
          acc[i][j] = __builtin_amdgcn_mfma_f32_16x16x32_bf16(af[i], bfr[j], acc[i][j], 0, 0, 0);
    }
  }

  const int colb = n0 + wn * 64;  // wave-uniform region selector (64-aligned)
  if (colb < QKN) {
    // ---- Q or K: RoPE via table on fp32 acc, optional scale, store to qk ----
    const float qscale = (colb < KOFF) ? SCALE_Q : 1.0f;
#pragma unroll
    for (int i = 0; i < 4; ++i) {
      const int rowb = m0 + wm * 64 + i * 16 + quad * 4;
      const int tb = rowb & (TT - 1);
#pragma unroll
      for (int j = 0; j < 2; ++j) {
        const int col = colb + j * 16 + l15;
        const int d = j * 16 + l15;  // 0..31
#pragma unroll
        for (int r = 0; r < 4; ++r) {
          const float2 cssn = ropeTab[(tb + r) * 32 + d];
          const float a = acc[i][j][r], b2 = acc[i][j + 2][r];
          const float qa = (a * cssn.x - b2 * cssn.y) * qscale;
          const float qb = (b2 * cssn.x + a * cssn.y) * qscale;
          unsigned short* p = qk + (size_t)(rowb + r) * QKN + col;
          p[0] = f2bf(qa);
          p[32] = f2bf(qb);
        }
      }
    }
  } else {
    // ---- V: transposed packed store  vT[col-2560][rowb..rowb+3] ----
#pragma unroll
    for (int i = 0; i < 4; ++i) {
      const int rowb = m0 + wm * 64 + i * 16 + quad * 4;
#pragma unroll
      for (int j = 0; j < 4; ++j) {
        const int col = colb + j * 16 + l15;
        ushort4 pk;
        pk.x = f2bf(acc[i][j][0]); pk.y = f2bf(acc[i][j][1]);
        pk.z = f2bf(acc[i][j][2]); pk.w = f2bf(acc[i][j][3]);
        *(ushort4*)(vT + (size_t)(col - 2560) * 4096 + rowb) = pk;
      }
    }
  }
}

// ---------- 1b: output projection NT GEMM (f32 out), grid 16x32 ----------
__global__ __launch_bounds__(256) void gemm_nt_f32(const unsigned short* __restrict__ A,
                                                   const unsigned short* __restrict__ Bw,
                                                   float* __restrict__ C,
                                                   int M, int N, int K) {
  __shared__ unsigned short As[128 * 64];
  __shared__ unsigned short Bs[128 * 64];
  const int tid = threadIdx.x;
  const int lane = tid & 63, w = tid >> 6;
  const int quad = lane >> 4, l15 = lane & 15;
  const int wm = w >> 1, wn = w & 1;
  // XCD-aware swizzle: grid 16x32, each XCD owns cols [2k, 2k+2)
  const int lin = blockIdx.y * 16 + blockIdx.x;
  const int sub = lin >> 3;
  const int m0 = (sub >> 1) * 128;
  const int n0 = ((lin & 7) * 2 + (sub & 1)) * 128;

  floatx4 acc[4][4];
#pragma unroll
  for (int i = 0; i < 4; ++i)
#pragma unroll
    for (int j = 0; j < 4; ++j) acc[i][j] = (floatx4){0.f, 0.f, 0.f, 0.f};

  const int ar = tid >> 3;
  const int ac = (((tid & 7) ^ (ar & 7)) * 8);
  const unsigned short* Abase = A + (size_t)(m0 + ar) * K + ac;
  const unsigned short* Bbase = Bw + (size_t)(n0 + ar) * K + ac;

  for (int k0 = 0; k0 < K; k0 += 64) {
    __syncthreads();
#pragma unroll
    for (int p = 0; p < 4; ++p) {
      load_lds16(Abase + (size_t)(p * 32) * K + k0, (char*)As + p * 4096 + tid * 16);
      load_lds16(Bbase + (size_t)(p * 32) * K + k0, (char*)Bs + p * 4096 + tid * 16);
    }
    __syncthreads();
#pragma unroll
    for (int ks = 0; ks < 2; ++ks) {
      short8 af[4], bfr[4];
      const int key = (((ks << 2) + quad) ^ (l15 & 7)) << 4;
#pragma unroll
      for (int i = 0; i < 4; ++i)
        af[i] = *(const short8*)((const char*)As + (wm * 64 + i * 16 + l15) * 128 + key);
#pragma unroll
      for (int j = 0; j < 4; ++j)
        bfr[j] = *(const short8*)((const char*)Bs + (wn * 64 + j * 16 + l15) * 128 + key);
#pragma unroll
      for (int i = 0; i < 4; ++i)
#pragma unroll
        for (int j = 0; j < 4; ++j)
          acc[i][j] = __builtin_amdgcn_mfma_f32_16x16x32_bf16(af[i], bfr[j], acc[i][j], 0, 0, 0);
    }
  }
#pragma unroll
  for (int i = 0; i < 4; ++i) {
    const int row = m0 + wm * 64 + i * 16 + quad * 4;
#pragma unroll
    for (int j = 0; j < 4; ++j) {
      const int col = n0 + wn * 64 + j * 16 + l15;
#pragma unroll
      for (int r = 0; r < 4; ++r)
        C[(size_t)(row + r) * N + col] = acc[i][j][r];
    }
  }
}

// ---------- 2: causal flash attention (fixed-max softmax, l via ones-MFMA) ----------
// grid (32, 8, 2) = (head-code, qtile-pair, batch); XCD (x&7) == kv-group hk.
// LDS: K[2] 2x8192 | V[2] 2x8192 | P 4x4608  = 51200 B
#define LDSA_K(buf) (lds + (buf) * 8192)
#define LDSA_V(buf) (lds + 16384 + (buf) * 8192)
#define LDSA_P      (lds + 32768)

__global__ __launch_bounds__(256) void attn_kernel(const unsigned short* __restrict__ qk,
                                                   const unsigned short* __restrict__ vT,
                                                   unsigned short* __restrict__ attn) {
  const int hcode = blockIdx.x;                  // 0..31
  const int h = (hcode & 7) * 4 + (hcode >> 3);  // XCD (hcode&7) serves hk == hcode&7
  const int bx = blockIdx.y;                     // 0..7 (q-tile pair)
  const int b = blockIdx.z;
  const int hk = h >> 2;
  const int tid = threadIdx.x;
  const int w = tid >> 6, lane = tid & 63, quad = lane >> 4, l15 = lane & 15;

  __shared__ char lds[51200];
  unsigned short* Pq = (unsigned short*)(LDSA_P + w * 4608);  // [32 q][72 kk]

  const int srow = tid >> 3;                    // staging row
  const int sgrp = ((tid & 7) ^ (srow & 7));    // swizzled source col-group

  const short8 ones = {16256, 16256, 16256, 16256, 16256, 16256, 16256, 16256};  // bf16 1.0

  for (int pass = 0; pass < 2; ++pass) {
    const int qt = pass ? (15 - bx) : bx;
    const size_t rowQ = (size_t)(b * TT + qt * 128);

    // ---- stage Q tile (128x64, swizzled) into K(0)+K(1) region ----
    {
      const unsigned short* qsrc = qk + (rowQ + srow) * QKN + h * 64 + sgrp * 8;
#pragma unroll
      for (int p = 0; p < 4; ++p)
        load_lds16(qsrc + (size_t)p * 32 * QKN, lds + p * 4096 + tid * 16);
    }
    __syncthreads();
    short8 qf[2][2];  // B-operand frags: Q[q=l15(+i*16)][d=ks*32+quad*8..]
#pragma unroll
    for (int i = 0; i < 2; ++i)
#pragma unroll
      for (int ks = 0; ks < 2; ++ks)
        qf[i][ks] = *(const short8*)(lds + (w * 32 + i * 16 + l15) * 128 +
                                     ((((ks << 2) + quad) ^ (l15 & 7)) << 4));
    __syncthreads();  // all waves done reading Q before K(0) overwrites

    floatx4 accO[2][4], accL[2];
#pragma unroll
    for (int i = 0; i < 2; ++i) {
      accL[i] = (floatx4){0.f, 0.f, 0.f, 0.f};
#pragma unroll
      for (int j = 0; j < 4; ++j) accO[i][j] = (floatx4){0.f, 0.f, 0.f, 0.f};
    }

    // ---- prologue: stage tile 0 (K + V, async, swizzled) ----
    {
      const unsigned short* ksrc =
          qk + (size_t)(b * TT + srow) * QKN + KOFF + hk * 64 + sgrp * 8;
      load_lds16(ksrc, LDSA_K(0) + tid * 16);
      load_lds16(ksrc + (size_t)32 * QKN, LDSA_K(0) + 4096 + tid * 16);
      const unsigned short* vsrc =
          vT + (size_t)(hk * 64 + srow) * 4096 + b * TT + sgrp * 8;
      load_lds16(vsrc, LDSA_V(0) + tid * 16);
      load_lds16(vsrc + (size_t)32 * 4096, LDSA_V(0) + 4096 + tid * 16);
    }
    __syncthreads();

    const int ktmax = 2 * qt + 1;
    for (int kt = 0; kt <= ktmax; ++kt) {
      const int cur = kt & 1, nxt = cur ^ 1;
      // ---- prefetch next tile (async; drained by end-of-iter barrier) ----
      if (kt < ktmax) {
        const unsigned short* ksrc =
            qk + (size_t)(b * TT + (kt + 1) * 64 + srow) * QKN + KOFF + hk * 64 + sgrp * 8;
        load_lds16(ksrc, LDSA_K(nxt) + tid * 16);
        load_lds16(ksrc + (size_t)32 * QKN, LDSA_K(nxt) + 4096 + tid * 16);
        const unsigned short* vsrc =
            vT + (size_t)(hk * 64 + srow) * 4096 + b * TT + (kt + 1) * 64 + sgrp * 8;
        load_lds16(vsrc, LDSA_V(nxt) + tid * 16);
        load_lds16(vsrc + (size_t)32 * 4096, LDSA_V(nxt) + 4096 + tid * 16);
      }

      // ---- S^T = K Q^T : D[kk_local][q_local]  (scale pre-folded into Q) ----
      const char* Ks = LDSA_K(cur);
      floatx4 st[2][4];  // [i=q-tile][jm=kk-tile]
#pragma unroll
      for (int jm = 0; jm < 4; ++jm) {
        const int krow = jm * 16 + l15;
        const short8 kf0 = *(const short8*)(Ks + krow * 128 + ((quad ^ (l15 & 7)) << 4));
        const short8 kf1 = *(const short8*)(Ks + krow * 128 + (((4 + quad) ^ (l15 & 7)) << 4));
#pragma unroll
        for (int i = 0; i < 2; ++i) {
          floatx4 z = (floatx4){0.f, 0.f, 0.f, 0.f};
          z = __builtin_amdgcn_mfma_f32_16x16x32_bf16(kf0, qf[i][0], z, 0, 0, 0);
          st[i][jm] = __builtin_amdgcn_mfma_f32_16x16x32_bf16(kf1, qf[i][1], z, 0, 0, 0);
        }
      }

      // ---- fixed-max softmax: P = exp2(st), masked to 0; store q-major (b64) ----
      const bool domask = (kt >= 2 * qt);
#pragma unroll
      for (int i = 0; i < 2; ++i) {
        const int qg = qt * 128 + w * 32 + i * 16 + l15;  // this lane's q (column)
#pragma unroll
        for (int jm = 0; jm < 4; ++jm) {
          float e0 = exp2f(st[i][jm][0]);
          float e1 = exp2f(st[i][jm][1]);
          float e2 = exp2f(st[i][jm][2]);
          float e3 = exp2f(st[i][jm][3]);
          if (domask) {
            const int kg = kt * 64 + jm * 16 + quad * 4;
            if (kg > qg) e0 = 0.f;
            if (kg + 1 > qg) e1 = 0.f;
            if (kg + 2 > qg) e2 = 0.f;
            if (kg + 3 > qg) e3 = 0.f;
          }
          ushort4 pk;
          pk.x = f2bf(e0); pk.y = f2bf(e1); pk.z = f2bf(e2); pk.w = f2bf(e3);
          *(ushort4*)(Pq + (i * 16 + l15) * 72 + jm * 16 + quad * 4) = pk;
        }
      }
      asm volatile("s_waitcnt lgkmcnt(0)" ::: "memory");  // wave-local P writes -> reads

      // ---- O += P V ; l += P . 1  (A=P, B=V^T / ones) ----
      const char* Vt = LDSA_V(cur);
#pragma unroll
      for (int ks = 0; ks < 2; ++ks) {
        short8 pf[2];
#pragma unroll
        for (int i2 = 0; i2 < 2; ++i2)
          pf[i2] = *(const short8*)(Pq + (i2 * 16 + l15) * 72 + ks * 32 + quad * 8);
        accL[0] = __builtin_amdgcn_mfma_f32_16x16x32_bf16(pf[0], ones, accL[0], 0, 0, 0);
        accL[1] = __builtin_amdgcn_mfma_f32_16x16x32_bf16(pf[1], ones, accL[1], 0, 0, 0);
#pragma unroll
        for (int jd = 0; jd < 4; ++jd) {
          const int d = jd * 16 + l15;
          const short8 vf = *(const short8*)(Vt + d * 128 +
                                             ((((ks << 2) + quad) ^ (l15 & 7)) << 4));
          accO[0][jd] = __builtin_amdgcn_mfma_f32_16x16x32_bf16(pf[0], vf, accO[0][jd], 0, 0, 0);
          accO[1][jd] = __builtin_amdgcn_mfma_f32_16x16x32_bf16(pf[1], vf, accO[1][jd], 0, 0, 0);
        }
      }
      __syncthreads();  // drains prefetch + protects cur-buffer overwrite next iter
    }

    // ---- epilogue: O / l -> attn  (accL C-layout rows match accO rows) ----
#pragma unroll
    for (int i2 = 0; i2 < 2; ++i2) {
#pragma unroll
      for (int jd = 0; jd < 4; ++jd) {
        const int col = h * 64 + jd * 16 + l15;
#pragma unroll
        for (int r = 0; r < 4; ++r) {
          const size_t row = rowQ + w * 32 + i2 * 16 + quad * 4 + r;
          attn[row * TC + col] = f2bf(accO[i2][jd][r] / accL[i2][r]);
        }
      }
    }
  }
}

// ---------- launch ----------
extern "C" void kernel_launch(void* const* d_in, const int* in_sizes, int n_in,
                              void* d_out, int out_size, void* d_ws, size_t ws_size,
                              hipStream_t stream) {
  const float* x = (const float*)d_in[0];
  const float* Wq = (const float*)d_in[1];
  const float* Wk = (const float*)d_in[2];
  const float* Wv = (const float*)d_in[3];
  const float* Wo = (const float*)d_in[4];
  float* out = (float*)d_out;

  char* ws = (char*)d_ws;
  unsigned short* xb   = (unsigned short*)(ws);               // 4096x2048 bf16
  unsigned short* wqkv = (unsigned short*)(ws + 16777216);    // 3072x2048 bf16
  unsigned short* wob  = (unsigned short*)(ws + 29360128);    // 2048x2048 bf16
  unsigned short* qk   = (unsigned short*)(ws + 37748736);    // 4096x2560 bf16 (Q|K, roped)
  unsigned short* vT   = (unsigned short*)(ws + 58720256);    // 512x4096 bf16 (V transposed)
  unsigned short* attn = (unsigned short*)(ws + 62914560);    // 4096x2048 bf16
  // rope table (512 KB) overlays the attn buffer: written by cast_all, read by
  // gemm_qkv, then overwritten by attn_kernel (all stream-ordered).
  float2* ropeTab = (float2*)(ws + 62914560);
  // total ws use: 79,691,776 bytes

  cast_all<<<18432, 256, 0, stream>>>(x, Wq, Wk, Wv, Wo, xb, wqkv, wob, ropeTab);
  gemm_qkv<<<dim3(24, 32), 256, 0, stream>>>(xb, wqkv, qk, vT, ropeTab);
  attn_kernel<<<dim3(32, 8, 2), 256, 0, stream>>>(qk, vT, attn);
  gemm_nt_f32<<<dim3(16, 32), 256, 0, stream>>>(attn, wob, out, 4096, TC, 2048);
}

// Round 6
// 293.146 us; speedup vs baseline: 1.9570x; 1.0162x over previous
//
#include <hip/hip_runtime.h>
#include <hip/hip_bf16.h>
#include <math.h>

// ---------- types / helpers ----------
typedef short short8 __attribute__((ext_vector_type(8)));
typedef float floatx4 __attribute__((ext_vector_type(4)));

typedef __attribute__((address_space(1))) unsigned int as1_u32;
typedef __attribute__((address_space(3))) unsigned int as3_u32;

__device__ __forceinline__ void load_lds16(const void* g, void* l) {
  // async 16B/lane global->LDS; HW dest = wave-uniform base + lane*16
  __builtin_amdgcn_global_load_lds((const as1_u32*)g, (as3_u32*)l, 16, 0, 0);
}

__device__ __forceinline__ unsigned short f2bf(float f) {
  __bf16 h = (__bf16)f;
  return __builtin_bit_cast(unsigned short, h);
}

// ---------- constants ----------
#define TB 2
#define TT 2048
#define TC 2048
#define QKN 2560    // qk row stride: 2048 Q + 512 K
#define KOFF 2048
#define SCALE_Q 0.18033688f  // (1/8) * log2(e), folded into Q at projection

// ---------- 0: cast fp32 -> bf16 (x, packed Wqkv, Wo) + rope table ----------
__global__ __launch_bounds__(256) void cast_all(
    const float* __restrict__ x, const float* __restrict__ wq,
    const float* __restrict__ wk, const float* __restrict__ wv,
    const float* __restrict__ wo,
    unsigned short* __restrict__ xb, unsigned short* __restrict__ wqkv,
    unsigned short* __restrict__ wob, float2* __restrict__ ropeTab) {
  // rope table: 2048 t x 32 d (cos,sin) = 512 KB, built by first 256 blocks
  if (blockIdx.x < 256) {
    const int idx = blockIdx.x * 256 + threadIdx.x;  // t*32+d
    const int t = idx >> 5, d = idx & 31;
    const float inv = exp2f((float)d * -0.4152410119f);  // 10000^(-d/32)
    float sn, cs;
    sincosf((float)t * inv, &sn, &cs);
    ropeTab[idx] = make_float2(cs, sn);
  }
  long i4 = (long)blockIdx.x * 256 + threadIdx.x;  // float4 index
  const float* src;
  unsigned short* dst;
  if (i4 < 2097152)      { src = x;  dst = xb; }
  else if (i4 < 3145728) { src = wq; dst = wqkv;           i4 -= 2097152; }
  else if (i4 < 3407872) { src = wk; dst = wqkv + 4194304; i4 -= 3145728; }
  else if (i4 < 3670016) { src = wv; dst = wqkv + 5242880; i4 -= 3407872; }
  else                   { src = wo; dst = wob;            i4 -= 3670016; }
  float4 v = ((const float4*)src)[i4];
  ushort4 o;
  o.x = f2bf(v.x); o.y = f2bf(v.y); o.z = f2bf(v.z); o.w = f2bf(v.w);
  ((ushort4*)dst)[i4] = o;
}

// ---------- 1: QKV GEMM with fused RoPE + Q-scale + V-transpose epilogue ----------
// C[M=4096, N=3072] = xb * wqkv^T.  Q cols [0,2048): rope+scale -> qk;
// K cols [2048,2560): rope -> qk; V cols [2560,3072): transposed -> vT[512][4096].
// Block swizzle: XCD (lin&7) owns a 3-wide N-stripe -> B stays L2-resident.
__global__ __launch_bounds__(256) void gemm_qkv(const unsigned short* __restrict__ A,
                                                const unsigned short* __restrict__ Bw,
                                                unsigned short* __restrict__ qk,
                                                unsigned short* __restrict__ vT,
                                                const float2* __restrict__ ropeTab) {
  __shared__ unsigned short As[128 * 64];
  __shared__ unsigned short Bs[128 * 64];
  const int K = 2048;
  const int tid = threadIdx.x;
  const int lane = tid & 63, w = tid >> 6;
  const int quad = lane >> 4, l15 = lane & 15;
  const int wm = w >> 1, wn = w & 1;
  // XCD-aware swizzle: grid 24x32, lin&7 = XCD, each XCD owns cols [3k, 3k+3)
  const int lin = blockIdx.y * 24 + blockIdx.x;
  const int sub = lin >> 3;
  const int m0 = (sub / 3) * 128;
  const int n0 = ((lin & 7) * 3 + sub % 3) * 128;

  floatx4 acc[4][4];
#pragma unroll
  for (int i = 0; i < 4; ++i)
#pragma unroll
    for (int j = 0; j < 4; ++j) acc[i][j] = (floatx4){0.f, 0.f, 0.f, 0.f};

  const int ar = tid >> 3;
  const int ac = (((tid & 7) ^ (ar & 7)) * 8);  // swizzled col-group
  const unsigned short* Abase = A + (size_t)(m0 + ar) * K + ac;
  const unsigned short* Bbase = Bw + (size_t)(n0 + ar) * K + ac;

  for (int k0 = 0; k0 < K; k0 += 64) {
    __syncthreads();
#pragma unroll
    for (int p = 0; p < 4; ++p) {
      load_lds16(Abase + (size_t)(p * 32) * K + k0, (char*)As + p * 4096 + tid * 16);
      load_lds16(Bbase + (size_t)(p * 32) * K + k0, (char*)Bs + p * 4096 + tid * 16);
    }
    __syncthreads();
#pragma unroll
    for (int ks = 0; ks < 2; ++ks) {
      short8 af[4], bfr[4];
      const int key = (((ks << 2) + quad) ^ (l15 & 7)) << 4;
#pragma unroll
      for (int i = 0; i < 4; ++i)
        af[i] = *(const short8*)((const char*)As + (wm * 64 + i * 16 + l15) * 128 + key);
#pragma unroll
      for (int j = 0; j < 4; ++j)
        bfr[j] = *(const short8*)((const char*)Bs + (wn * 64 + j * 16 + l15) * 128 + key);
#pragma unroll
      for (int i = 0; i < 4; ++i)
#pragma unroll
        for (int j = 0; j < 4; ++j)
          acc[i][j] = __builtin_amdgcn_mfma_f32_16x16x32_bf16(af[i], bfr[j], acc[i][j], 0, 0, 0);
    }
  }

  const int colb = n0 + wn * 64;  // wave-uniform region selector (64-aligned)
  if (colb < QKN) {
    // ---- Q or K: RoPE via table on fp32 acc, optional scale, store to qk ----
    const float qscale = (colb < KOFF) ? SCALE_Q : 1.0f;
#pragma unroll
    for (int i = 0; i < 4; ++i) {
      const int rowb = m0 + wm * 64 + i * 16 + quad * 4;
      const int tb = rowb & (TT - 1);
#pragma unroll
      for (int j = 0; j < 2; ++j) {
        const int col = colb + j * 16 + l15;
        const int d = j * 16 + l15;  // 0..31
#pragma unroll
        for (int r = 0; r < 4; ++r) {
          const float2 cssn = ropeTab[(tb + r) * 32 + d];
          const float a = acc[i][j][r], b2 = acc[i][j + 2][r];
          const float qa = (a * cssn.x - b2 * cssn.y) * qscale;
          const float qb = (b2 * cssn.x + a * cssn.y) * qscale;
          unsigned short* p = qk + (size_t)(rowb + r) * QKN + col;
          p[0] = f2bf(qa);
          p[32] = f2bf(qb);
        }
      }
    }
  } else {
    // ---- V: transposed packed store  vT[col-2560][rowb..rowb+3] ----
#pragma unroll
    for (int i = 0; i < 4; ++i) {
      const int rowb = m0 + wm * 64 + i * 16 + quad * 4;
#pragma unroll
      for (int j = 0; j < 4; ++j) {
        const int col = colb + j * 16 + l15;
        ushort4 pk;
        pk.x = f2bf(acc[i][j][0]); pk.y = f2bf(acc[i][j][1]);
        pk.z = f2bf(acc[i][j][2]); pk.w = f2bf(acc[i][j][3]);
        *(ushort4*)(vT + (size_t)(col - 2560) * 4096 + rowb) = pk;
      }
    }
  }
}

// ---------- 1b: output projection NT GEMM (f32 out), grid 16x32 ----------
__global__ __launch_bounds__(256) void gemm_nt_f32(const unsigned short* __restrict__ A,
                                                   const unsigned short* __restrict__ Bw,
                                                   float* __restrict__ C,
                                                   int M, int N, int K) {
  __shared__ unsigned short As[128 * 64];
  __shared__ unsigned short Bs[128 * 64];
  const int tid = threadIdx.x;
  const int lane = tid & 63, w = tid >> 6;
  const int quad = lane >> 4, l15 = lane & 15;
  const int wm = w >> 1, wn = w & 1;
  // XCD-aware swizzle: grid 16x32, each XCD owns cols [2k, 2k+2)
  const int lin = blockIdx.y * 16 + blockIdx.x;
  const int sub = lin >> 3;
  const int m0 = (sub >> 1) * 128;
  const int n0 = ((lin & 7) * 2 + (sub & 1)) * 128;

  floatx4 acc[4][4];
#pragma unroll
  for (int i = 0; i < 4; ++i)
#pragma unroll
    for (int j = 0; j < 4; ++j) acc[i][j] = (floatx4){0.f, 0.f, 0.f, 0.f};

  const int ar = tid >> 3;
  const int ac = (((tid & 7) ^ (ar & 7)) * 8);
  const unsigned short* Abase = A + (size_t)(m0 + ar) * K + ac;
  const unsigned short* Bbase = Bw + (size_t)(n0 + ar) * K + ac;

  for (int k0 = 0; k0 < K; k0 += 64) {
    __syncthreads();
#pragma unroll
    for (int p = 0; p < 4; ++p) {
      load_lds16(Abase + (size_t)(p * 32) * K + k0, (char*)As + p * 4096 + tid * 16);
      load_lds16(Bbase + (size_t)(p * 32) * K + k0, (char*)Bs + p * 4096 + tid * 16);
    }
    __syncthreads();
#pragma unroll
    for (int ks = 0; ks < 2; ++ks) {
      short8 af[4], bfr[4];
      const int key = (((ks << 2) + quad) ^ (l15 & 7)) << 4;
#pragma unroll
      for (int i = 0; i < 4; ++i)
        af[i] = *(const short8*)((const char*)As + (wm * 64 + i * 16 + l15) * 128 + key);
#pragma unroll
      for (int j = 0; j < 4; ++j)
        bfr[j] = *(const short8*)((const char*)Bs + (wn * 64 + j * 16 + l15) * 128 + key);
#pragma unroll
      for (int i = 0; i < 4; ++i)
#pragma unroll
        for (int j = 0; j < 4; ++j)
          acc[i][j] = __builtin_amdgcn_mfma_f32_16x16x32_bf16(af[i], bfr[j], acc[i][j], 0, 0, 0);
    }
  }
#pragma unroll
  for (int i = 0; i < 4; ++i) {
    const int row = m0 + wm * 64 + i * 16 + quad * 4;
#pragma unroll
    for (int j = 0; j < 4; ++j) {
      const int col = n0 + wn * 64 + j * 16 + l15;
#pragma unroll
      for (int r = 0; r < 4; ++r)
        C[(size_t)(row + r) * N + col] = acc[i][j][r];
    }
  }
}

// ---------- 2: causal flash attention v6 ----------
// grid (8, 32, 2) = (qtile-pair, head, batch) -- R4 mapping (R5 XCD swizzle
// regressed: lockstep K/V traversal convoyed on first-touch lines).
// kv-loop unrolled by 2 (trip count 2qt+2 always even): compile-time buffer
// indices, pointer-increment prefetch, mask only in last 2 tiles.
// LDS: K[2] 2x8192 | V[2] 2x8192 | P 4x4608  = 51200 B
__global__ __launch_bounds__(256) void attn_kernel(const unsigned short* __restrict__ qk,
                                                   const unsigned short* __restrict__ vT,
                                                   unsigned short* __restrict__ attn) {
  const int bx = blockIdx.x;  // 0..7 (q-tile pair)
  const int h = blockIdx.y, b = blockIdx.z;
  const int hk = h >> 2;
  const int tid = threadIdx.x;
  const int w = tid >> 6, lane = tid & 63, quad = lane >> 4, l15 = lane & 15;

  __shared__ char lds[51200];
  unsigned short* Pq = (unsigned short*)(lds + 32768 + w * 4608);  // [32 q][72 kk]

  const int srow = tid >> 3;                    // staging row
  const int sgrp = ((tid & 7) ^ (srow & 7));    // swizzled source col-group
  const int relbase = w * 32 + l15;             // for causal mask (q local)

  const short8 ones = {16256, 16256, 16256, 16256, 16256, 16256, 16256, 16256};  // bf16 1.0

  for (int pass = 0; pass < 2; ++pass) {
    const int qt = pass ? (15 - bx) : bx;
    const size_t rowQ = (size_t)(b * TT + qt * 128);

    // ---- stage Q tile (128x64, swizzled) into K/V region ----
    {
      const unsigned short* qsrc = qk + (rowQ + srow) * QKN + h * 64 + sgrp * 8;
#pragma unroll
      for (int p = 0; p < 4; ++p)
        load_lds16(qsrc + (size_t)p * 32 * QKN, lds + p * 4096 + tid * 16);
    }
    __syncthreads();
    short8 qf[2][2];  // B-operand frags: Q[q=l15(+i*16)][d=ks*32+quad*8..]
#pragma unroll
    for (int i = 0; i < 2; ++i)
#pragma unroll
      for (int ks = 0; ks < 2; ++ks)
        qf[i][ks] = *(const short8*)(lds + (w * 32 + i * 16 + l15) * 128 +
                                     ((((ks << 2) + quad) ^ (l15 & 7)) << 4));
    __syncthreads();  // all waves done reading Q before K(0)/V(0) overwrite

    floatx4 accO[2][4], accL[2];
#pragma unroll
    for (int i = 0; i < 2; ++i) {
      accL[i] = (floatx4){0.f, 0.f, 0.f, 0.f};
#pragma unroll
      for (int j = 0; j < 4; ++j) accO[i][j] = (floatx4){0.f, 0.f, 0.f, 0.f};
    }

    // ---- prefetch pointers (advance by one 64-row tile per step) ----
    const unsigned short* kptr =
        qk + (size_t)(b * TT + srow) * QKN + KOFF + hk * 64 + sgrp * 8;
    const unsigned short* vptr =
        vT + (size_t)(hk * 64 + srow) * 4096 + b * TT + sgrp * 8;

    // ---- prologue: stage tile 0 into buf0 ----
    load_lds16(kptr, lds + tid * 16);
    load_lds16(kptr + (size_t)32 * QKN, lds + 4096 + tid * 16);
    load_lds16(vptr, lds + 16384 + tid * 16);
    load_lds16(vptr + (size_t)32 * 4096, lds + 16384 + 4096 + tid * 16);
    kptr += (size_t)64 * QKN;
    vptr += 64;
    __syncthreads();

    // one kv-tile step; BUF/PREF/MREL become compile-time after inlining
    auto step = [&](const int BUF, const bool PREF, const int MREL) {
      if (PREF) {
        char* kd = lds + ((BUF ^ 1) * 8192);
        char* vd = lds + 16384 + ((BUF ^ 1) * 8192);
        load_lds16(kptr, kd + tid * 16);
        load_lds16(kptr + (size_t)32 * QKN, kd + 4096 + tid * 16);
        load_lds16(vptr, vd + tid * 16);
        load_lds16(vptr + (size_t)32 * 4096, vd + 4096 + tid * 16);
        kptr += (size_t)64 * QKN;
        vptr += 64;
      }

      // ---- S^T = K Q^T : D[kk_local][q_local] (scale pre-folded into Q) ----
      const char* Ks = lds + BUF * 8192;
      floatx4 st[2][4];  // [i=q-tile][jm=kk-tile]
#pragma unroll
      for (int jm = 0; jm < 4; ++jm) {
        const int krow = jm * 16 + l15;
        const short8 kf0 = *(const short8*)(Ks + krow * 128 + ((quad ^ (l15 & 7)) << 4));
        const short8 kf1 = *(const short8*)(Ks + krow * 128 + (((4 + quad) ^ (l15 & 7)) << 4));
#pragma unroll
        for (int i = 0; i < 2; ++i) {
          floatx4 z = (floatx4){0.f, 0.f, 0.f, 0.f};
          z = __builtin_amdgcn_mfma_f32_16x16x32_bf16(kf0, qf[i][0], z, 0, 0, 0);
          st[i][jm] = __builtin_amdgcn_mfma_f32_16x16x32_bf16(kf1, qf[i][1], z, 0, 0, 0);
        }
      }

      // ---- hoist V-fragment LDS reads: latency overlaps softmax VALU ----
      const char* Vt = lds + 16384 + BUF * 8192;
      short8 vf[2][4];
#pragma unroll
      for (int ks = 0; ks < 2; ++ks)
#pragma unroll
        for (int jd = 0; jd < 4; ++jd) {
          const int d = jd * 16 + l15;
          vf[ks][jd] = *(const short8*)(Vt + d * 128 +
                                        ((((ks << 2) + quad) ^ (l15 & 7)) << 4));
        }

      // ---- fixed-max softmax: P = exp2(st); mask only when MREL >= 0 ----
#pragma unroll
      for (int i = 0; i < 2; ++i) {
#pragma unroll
        for (int jm = 0; jm < 4; ++jm) {
          float e0 = exp2f(st[i][jm][0]);
          float e1 = exp2f(st[i][jm][1]);
          float e2 = exp2f(st[i][jm][2]);
          float e3 = exp2f(st[i][jm][3]);
          if (MREL >= 0) {
            const int rel = relbase + i * 16 - MREL;  // lane's local q
            const int kg = jm * 16 + quad * 4;
            if (kg > rel) e0 = 0.f;
            if (kg + 1 > rel) e1 = 0.f;
            if (kg + 2 > rel) e2 = 0.f;
            if (kg + 3 > rel) e3 = 0.f;
          }
          ushort4 pk;
          pk.x = f2bf(e0); pk.y = f2bf(e1); pk.z = f2bf(e2); pk.w = f2bf(e3);
          *(ushort4*)(Pq + (i * 16 + l15) * 72 + jm * 16 + quad * 4) = pk;
        }
      }
      asm volatile("s_waitcnt lgkmcnt(0)" ::: "memory");  // wave-local P w->r

      // ---- O += P V ; l += P . 1 ----
#pragma unroll
      for (int ks = 0; ks < 2; ++ks) {
        short8 pf[2];
#pragma unroll
        for (int i2 = 0; i2 < 2; ++i2)
          pf[i2] = *(const short8*)(Pq + (i2 * 16 + l15) * 72 + ks * 32 + quad * 8);
        accL[0] = __builtin_amdgcn_mfma_f32_16x16x32_bf16(pf[0], ones, accL[0], 0, 0, 0);
        accL[1] = __builtin_amdgcn_mfma_f32_16x16x32_bf16(pf[1], ones, accL[1], 0, 0, 0);
#pragma unroll
        for (int jd = 0; jd < 4; ++jd) {
          accO[0][jd] = __builtin_amdgcn_mfma_f32_16x16x32_bf16(pf[0], vf[ks][jd], accO[0][jd], 0, 0, 0);
          accO[1][jd] = __builtin_amdgcn_mfma_f32_16x16x32_bf16(pf[1], vf[ks][jd], accO[1][jd], 0, 0, 0);
        }
      }
      __syncthreads();  // drains prefetch + protects buffer overwrite
    };

    // steady: 2*qt unmasked tiles (pairs), then 2 masked diagonal tiles
    for (int t2 = 0; t2 < qt; ++t2) {
      step(0, true, -1);
      step(1, true, -1);
    }
    step(0, true, 0);
    step(1, false, 64);

    // ---- epilogue: O / l -> attn  (accL C-layout rows match accO rows) ----
#pragma unroll
    for (int i2 = 0; i2 < 2; ++i2) {
#pragma unroll
      for (int jd = 0; jd < 4; ++jd) {
        const int col = h * 64 + jd * 16 + l15;
#pragma unroll
        for (int r = 0; r < 4; ++r) {
          const size_t row = rowQ + w * 32 + i2 * 16 + quad * 4 + r;
          attn[row * TC + col] = f2bf(accO[i2][jd][r] / accL[i2][r]);
        }
      }
    }
  }
}

// ---------- launch ----------
extern "C" void kernel_launch(void* const* d_in, const int* in_sizes, int n_in,
                              void* d_out, int out_size, void* d_ws, size_t ws_size,
                              hipStream_t stream) {
  const float* x = (const float*)d_in[0];
  const float* Wq = (const float*)d_in[1];
  const float* Wk = (const float*)d_in[2];
  const float* Wv = (const float*)d_in[3];
  const float* Wo = (const float*)d_in[4];
  float* out = (float*)d_out;

  char* ws = (char*)d_ws;
  unsigned short* xb   = (unsigned short*)(ws);               // 4096x2048 bf16
  unsigned short* wqkv = (unsigned short*)(ws + 16777216);    // 3072x2048 bf16
  unsigned short* wob  = (unsigned short*)(ws + 29360128);    // 2048x2048 bf16
  unsigned short* qk   = (unsigned short*)(ws + 37748736);    // 4096x2560 bf16 (Q|K, roped)
  unsigned short* vT   = (unsigned short*)(ws + 58720256);    // 512x4096 bf16 (V transposed)
  unsigned short* attn = (unsigned short*)(ws + 62914560);    // 4096x2048 bf16
  // rope table (512 KB) overlays the attn buffer: written by cast_all, read by
  // gemm_qkv, then overwritten by attn_kernel (all stream-ordered).
  float2* ropeTab = (float2*)(ws + 62914560);
  // total ws use: 79,691,776 bytes

  cast_all<<<18432, 256, 0, stream>>>(x, Wq, Wk, Wv, Wo, xb, wqkv, wob, ropeTab);
  gemm_qkv<<<dim3(24, 32), 256, 0, stream>>>(xb, wqkv, qk, vT, ropeTab);
  attn_kernel<<<dim3(8, 32, 2), 256, 0, stream>>>(qk, vT, attn);
  gemm_nt_f32<<<dim3(16, 32), 256, 0, stream>>>(attn, wob, out, 4096, TC, 2048);
}